// Round 1
// baseline (535.881 us; speedup 1.0000x reference)
//
#include <hip/hip_runtime.h>

#define F_IN 128
#define F_OUT 64

__device__ __forceinline__ float leaky(float v) { return v > 0.f ? v : 0.01f * v; }

// ---------------- Kernel 1: h = x @ W  (x:[N,128], W:[128,64] -> h:[N,64]) ----------------
__global__ __launch_bounds__(256) void gemm_xw(const float* __restrict__ x,
                                               const float* __restrict__ W,
                                               float* __restrict__ h, int N) {
    __shared__ float w_lds[F_IN][F_OUT];   // 32 KB
    __shared__ float x_lds[4][F_IN];       // 2 KB
    for (int i = threadIdx.x; i < F_IN * F_OUT; i += 256)
        w_lds[i / F_OUT][i % F_OUT] = W[i];
    __syncthreads();

    const int row0 = blockIdx.x * 64;
    const int r_sub = threadIdx.x >> 6;    // 0..3 (wave-uniform)
    const int col = threadIdx.x & 63;

    for (int it = 0; it < 16; ++it) {
        const int row_base = row0 + it * 4;
        __syncthreads();   // protect x_lds from previous iteration's readers
        for (int i = threadIdx.x; i < 4 * F_IN; i += 256) {
            const int r = i >> 7, k = i & 127;
            const int rr = row_base + r;
            x_lds[r][k] = (rr < N) ? x[(size_t)rr * F_IN + k] : 0.f;
        }
        __syncthreads();
        const int row = row_base + r_sub;
        if (row < N) {
            float acc = 0.f;
#pragma unroll
            for (int k = 0; k < F_IN; ++k)
                acc = fmaf(x_lds[r_sub][k], w_lds[k][col], acc);  // x broadcast, w stride-1
            h[(size_t)row * F_OUT + col] = acc;
        }
    }
}

// ---------------- Kernel 2: per-edge score + scatter ----------------
// One wave per edge; lane = feature index. relu_bt == leaky_relu (threshold never clips).
__global__ __launch_bounds__(256) void edge_kernel(const int* __restrict__ ei,
                                                   const float* __restrict__ h,
                                                   const float* __restrict__ a,
                                                   float* __restrict__ hprime,   // accumulates in d_out
                                                   float* __restrict__ rowsum,
                                                   int E) {
    const int lane = threadIdx.x & 63;
    const int wave = (int)((blockIdx.x * blockDim.x + threadIdx.x) >> 6);
    const int nwaves = (int)((gridDim.x * blockDim.x) >> 6);

    const float a0 = a[lane];
    const float a1 = a[64 + lane];
    const float a2 = a[128 + lane];
    const float a3 = a[192 + lane];

    for (int e = wave; e < E; e += nwaves) {
        const int s = ei[e];
        const int d = ei[E + e];
        const float hs = h[(size_t)s * F_OUT + lane];
        const float hd = h[(size_t)d * F_OUT + lane];

        float part = hs * a0 + hd * a1 + leaky(hs + hd) * a2 + leaky(hs - hd) * a3;
#pragma unroll
        for (int m = 1; m < 64; m <<= 1)
            part += __shfl_xor(part, m);

        const float ee = expf(-leaky(part));

        atomicAdd(&hprime[(size_t)s * F_OUT + lane], ee * hd);
        if (lane == 0) atomicAdd(&rowsum[s], ee);
    }
}

// ---------------- Kernel 3: out = hprime / (rowsum + 1e-16) ----------------
__global__ __launch_bounds__(256) void finalize(float* __restrict__ out,
                                                const float* __restrict__ rowsum,
                                                int total) {
    const int i = blockIdx.x * blockDim.x + threadIdx.x;
    if (i < total) out[i] = out[i] / (rowsum[i >> 6] + 1e-16f);
}

extern "C" void kernel_launch(void* const* d_in, const int* in_sizes, int n_in,
                              void* d_out, int out_size, void* d_ws, size_t ws_size,
                              hipStream_t stream) {
    const float* x  = (const float*)d_in[0];
    const int*   ei = (const int*)d_in[1];
    const float* W  = (const float*)d_in[2];
    const float* a  = (const float*)d_in[3];

    const int N = in_sizes[0] / F_IN;
    const int E = in_sizes[1] / 2;

    float* out    = (float*)d_out;
    float* h      = (float*)d_ws;                                   // N*64 floats
    float* rowsum = (float*)((char*)d_ws + (size_t)N * F_OUT * 4);  // N floats

    hipMemsetAsync(d_out, 0, (size_t)N * F_OUT * sizeof(float), stream);
    hipMemsetAsync(rowsum, 0, (size_t)N * sizeof(float), stream);

    gemm_xw<<<(N + 63) / 64, 256, 0, stream>>>(x, W, h, N);
    edge_kernel<<<2048, 256, 0, stream>>>(ei, h, a, out, rowsum, E);
    finalize<<<(N * F_OUT + 255) / 256, 256, 0, stream>>>(out, rowsum, N * F_OUT);
}

// Round 2
// 507.009 us; speedup vs baseline: 1.0569x; 1.0569x over previous
//
#include <hip/hip_runtime.h>

#define F_IN 128
#define F_OUT 64

__device__ __forceinline__ float leaky(float v) { return v > 0.f ? v : 0.01f * v; }

// ---------------- Kernel 1: h = x @ W  (wave per row; W in LDS, x wave-uniform) ----------------
__global__ __launch_bounds__(256) void gemm_xw(const float* __restrict__ x,
                                               const float* __restrict__ W,
                                               float* __restrict__ h, int N) {
    __shared__ float w_lds[F_IN][F_OUT];   // 32 KB
    for (int i = threadIdx.x; i < F_IN * F_OUT; i += 256)
        w_lds[i / F_OUT][i % F_OUT] = W[i];
    __syncthreads();

    const int lane = threadIdx.x & 63;
    int row = blockIdx.x * 4 + (threadIdx.x >> 6);
    row = __builtin_amdgcn_readfirstlane(row);
    if (row >= N) return;

    const float4* xr = (const float4*)(x + (size_t)row * F_IN);
    float acc = 0.f;
#pragma unroll
    for (int k4 = 0; k4 < F_IN / 4; ++k4) {
        const float4 xv = xr[k4];   // wave-uniform load
        acc = fmaf(xv.x, w_lds[k4 * 4 + 0][lane], acc);
        acc = fmaf(xv.y, w_lds[k4 * 4 + 1][lane], acc);
        acc = fmaf(xv.z, w_lds[k4 * 4 + 2][lane], acc);
        acc = fmaf(xv.w, w_lds[k4 * 4 + 3][lane], acc);
    }
    h[(size_t)row * F_OUT + lane] = acc;
}

// ---------------- CSR build ----------------
__global__ __launch_bounds__(256) void hist_kernel(const int* __restrict__ ei,
                                                   unsigned* __restrict__ cnt, int E) {
    const int e = blockIdx.x * 256 + threadIdx.x;
    if (e < E) atomicAdd(&cnt[ei[e]], 1u);
}

// per-block sums of 2048 counts
__global__ __launch_bounds__(256) void scan1(const unsigned* __restrict__ cnt,
                                             unsigned* __restrict__ bsum, int n) {
    __shared__ unsigned lds[256];
    const int t = threadIdx.x;
    const int base = blockIdx.x * 2048 + t * 8;
    unsigned s = 0;
#pragma unroll
    for (int i = 0; i < 8; ++i) { const int idx = base + i; if (idx < n) s += cnt[idx]; }
    lds[t] = s; __syncthreads();
    for (int st = 128; st > 0; st >>= 1) {
        if (t < st) lds[t] += lds[t + st];
        __syncthreads();
    }
    if (t == 0) bsum[blockIdx.x] = lds[0];
}

// exclusive scan of block sums (nb <= 128); writes grand total to off[n]
__global__ __launch_bounds__(128) void scan2(unsigned* __restrict__ bsum,
                                             unsigned* __restrict__ off, int nb, int n) {
    __shared__ unsigned lds[128];
    const int t = threadIdx.x;
    if (t < nb) lds[t] = bsum[t];
    __syncthreads();
    if (t == 0) {
        unsigned run = 0;
        for (int i = 0; i < nb; ++i) { const unsigned v = lds[i]; lds[i] = run; run += v; }
        off[n] = run;
    }
    __syncthreads();
    if (t < nb) bsum[t] = lds[t];
}

// block-local exclusive scan + block offset -> off[] and cursor[]
__global__ __launch_bounds__(256) void scan3(const unsigned* __restrict__ cnt,
                                             const unsigned* __restrict__ bsum,
                                             unsigned* __restrict__ off,
                                             unsigned* __restrict__ cursor, int n) {
    __shared__ unsigned lds[256];
    const int t = threadIdx.x;
    const int base = blockIdx.x * 2048 + t * 8;
    unsigned v[8]; unsigned s = 0;
#pragma unroll
    for (int i = 0; i < 8; ++i) { const int idx = base + i; v[i] = (idx < n) ? cnt[idx] : 0u; s += v[i]; }
    lds[t] = s; __syncthreads();
    // inclusive Hillis-Steele over 256 thread sums
    for (int st = 1; st < 256; st <<= 1) {
        const unsigned add = (t >= st) ? lds[t - st] : 0u;
        __syncthreads();
        lds[t] += add;
        __syncthreads();
    }
    unsigned excl = (t > 0 ? lds[t - 1] : 0u) + bsum[blockIdx.x];
#pragma unroll
    for (int i = 0; i < 8; ++i) {
        const int idx = base + i;
        if (idx < n) { off[idx] = excl; cursor[idx] = excl; excl += v[i]; }
    }
}

__global__ __launch_bounds__(256) void scatter_kernel(const int* __restrict__ ei,
                                                      unsigned* __restrict__ cursor,
                                                      int* __restrict__ sdst, int E) {
    const int e = blockIdx.x * 256 + threadIdx.x;
    if (e >= E) return;
    const int s = ei[e];
    const int d = ei[E + e];
    const unsigned pos = atomicAdd(&cursor[s], 1u);
    sdst[pos] = d;
}

// ---------------- Fused per-node score + aggregate + divide ----------------
__global__ __launch_bounds__(256) void node_kernel(const unsigned* __restrict__ off,
                                                   const int* __restrict__ sdst,
                                                   const float* __restrict__ h,
                                                   const float* __restrict__ a,
                                                   float* __restrict__ out, int N) {
    const int lane = threadIdx.x & 63;
    const int node = (int)((blockIdx.x * (unsigned)blockDim.x + threadIdx.x) >> 6);
    if (node >= N) return;

    const float a0 = a[lane];
    const float a1 = a[64 + lane];
    const float a2 = a[128 + lane];
    const float a3 = a[192 + lane];

    const int beg = (int)off[node];
    const int end = (int)off[node + 1];
    const float hs = h[(size_t)node * F_OUT + lane];
    const float hs_a0 = hs * a0;

    float acc = 0.f, rsum = 0.f;
    float hd_next = 0.f;
    if (beg < end) {
        const int d0 = sdst[beg];
        hd_next = h[(size_t)d0 * F_OUT + lane];
    }
    for (int e = beg; e < end; ++e) {
        const float hd = hd_next;
        if (e + 1 < end) {
            const int dn = sdst[e + 1];               // broadcast load
            hd_next = h[(size_t)dn * F_OUT + lane];   // prefetch next gather
        }
        float part = hs_a0 + hd * a1 + leaky(hs + hd) * a2 + leaky(hs - hd) * a3;
#pragma unroll
        for (int m = 1; m < 64; m <<= 1)
            part += __shfl_xor(part, m);
        const float ee = expf(-leaky(part));
        acc = fmaf(ee, hd, acc);
        rsum += ee;
    }
    out[(size_t)node * F_OUT + lane] = acc / (rsum + 1e-16f);
}

// ---------------- Fallback path (round-1 atomic version) ----------------
__global__ __launch_bounds__(256) void edge_kernel(const int* __restrict__ ei,
                                                   const float* __restrict__ h,
                                                   const float* __restrict__ a,
                                                   float* __restrict__ hprime,
                                                   float* __restrict__ rowsum,
                                                   int E) {
    const int lane = threadIdx.x & 63;
    const int wave = (int)((blockIdx.x * blockDim.x + threadIdx.x) >> 6);
    const int nwaves = (int)((gridDim.x * blockDim.x) >> 6);
    const float a0 = a[lane], a1 = a[64 + lane], a2 = a[128 + lane], a3 = a[192 + lane];
    for (int e = wave; e < E; e += nwaves) {
        const int s = ei[e];
        const int d = ei[E + e];
        const float hs = h[(size_t)s * F_OUT + lane];
        const float hd = h[(size_t)d * F_OUT + lane];
        float part = hs * a0 + hd * a1 + leaky(hs + hd) * a2 + leaky(hs - hd) * a3;
#pragma unroll
        for (int m = 1; m < 64; m <<= 1) part += __shfl_xor(part, m);
        const float ee = expf(-leaky(part));
        atomicAdd(&hprime[(size_t)s * F_OUT + lane], ee * hd);
        if (lane == 0) atomicAdd(&rowsum[s], ee);
    }
}

__global__ __launch_bounds__(256) void finalize(float* __restrict__ out,
                                                const float* __restrict__ rowsum,
                                                int total) {
    const int i = blockIdx.x * blockDim.x + threadIdx.x;
    if (i < total) out[i] = out[i] / (rowsum[i >> 6] + 1e-16f);
}

static inline size_t align_up(size_t v, size_t a) { return (v + a - 1) & ~(a - 1); }

extern "C" void kernel_launch(void* const* d_in, const int* in_sizes, int n_in,
                              void* d_out, int out_size, void* d_ws, size_t ws_size,
                              hipStream_t stream) {
    const float* x  = (const float*)d_in[0];
    const int*   ei = (const int*)d_in[1];
    const float* W  = (const float*)d_in[2];
    const float* a  = (const float*)d_in[3];

    const int N = in_sizes[0] / F_IN;
    const int E = in_sizes[1] / 2;
    float* out = (float*)d_out;

    // workspace carve-up
    char* ws = (char*)d_ws;
    size_t off_b    = align_up((size_t)N * F_OUT * 4, 256);            // h
    size_t cursor_b = off_b + align_up(((size_t)N + 1) * 4, 256);      // off
    size_t sdst_b   = cursor_b + align_up((size_t)N * 4, 256);         // cursor
    size_t cnt_b    = sdst_b + align_up((size_t)E * 4, 256);           // sdst
    size_t bsum_b   = cnt_b + align_up((size_t)N * 4, 256);            // cnt
    size_t need     = bsum_b + align_up(4096, 256);                    // bsum

    float* h = (float*)ws;

    if (ws_size >= need) {
        unsigned* off    = (unsigned*)(ws + off_b);
        unsigned* cursor = (unsigned*)(ws + cursor_b);
        int*      sdst   = (int*)(ws + sdst_b);
        unsigned* cnt    = (unsigned*)(ws + cnt_b);
        unsigned* bsum   = (unsigned*)(ws + bsum_b);

        const int nb = (N + 2047) / 2048;   // 49 for N=100000

        hipMemsetAsync(cnt, 0, (size_t)N * 4, stream);
        gemm_xw<<<(N + 3) / 4, 256, 0, stream>>>(x, W, h, N);
        hist_kernel<<<(E + 255) / 256, 256, 0, stream>>>(ei, cnt, E);
        scan1<<<nb, 256, 0, stream>>>(cnt, bsum, N);
        scan2<<<1, 128, 0, stream>>>(bsum, off, nb, N);
        scan3<<<nb, 256, 0, stream>>>(cnt, bsum, off, cursor, N);
        scatter_kernel<<<(E + 255) / 256, 256, 0, stream>>>(ei, cursor, sdst, E);
        node_kernel<<<((size_t)N * 64 + 255) / 256, 256, 0, stream>>>(off, sdst, h, a, out, N);
    } else {
        // fallback: round-1 atomic path
        float* rowsum = (float*)(ws + off_b);
        hipMemsetAsync(d_out, 0, (size_t)N * F_OUT * sizeof(float), stream);
        hipMemsetAsync(rowsum, 0, (size_t)N * sizeof(float), stream);
        gemm_xw<<<(N + 3) / 4, 256, 0, stream>>>(x, W, h, N);
        edge_kernel<<<2048, 256, 0, stream>>>(ei, h, a, out, rowsum, E);
        finalize<<<((size_t)N * F_OUT + 255) / 256, 256, 0, stream>>>(out, rowsum, N * F_OUT);
    }
}

// Round 3
// 434.888 us; speedup vs baseline: 1.2322x; 1.1658x over previous
//
#include <hip/hip_runtime.h>

#define F_IN 128
#define F_OUT 64

__device__ __forceinline__ float leaky(float v) {
    return fmaf(0.495f, fabsf(v), 0.505f * v);   // == leaky_relu(v, 0.01)
}

// score contribution that must be lane-reduced (per edge)
__device__ __forceinline__ float edge_part(float hs, float hd, float a1, float a2, float a3) {
    float p = hd * a1;
    p = fmaf(leaky(hs + hd), a2, p);
    p = fmaf(leaky(hs - hd), a3, p);
    return p;
}

// ---------------- Kernel 1: h = x @ W  (wave per row; W in LDS, x wave-uniform) ----------------
__global__ __launch_bounds__(256) void gemm_xw(const float* __restrict__ x,
                                               const float* __restrict__ W,
                                               float* __restrict__ h, int N) {
    __shared__ float w_lds[F_IN][F_OUT];   // 32 KB
    for (int i = threadIdx.x; i < F_IN * F_OUT; i += 256)
        w_lds[i >> 6][i & 63] = W[i];
    __syncthreads();

    const int lane = threadIdx.x & 63;
    int row = blockIdx.x * 4 + (threadIdx.x >> 6);
    row = __builtin_amdgcn_readfirstlane(row);
    if (row >= N) return;

    const float4* xr = (const float4*)(x + (size_t)row * F_IN);
    float acc = 0.f;
#pragma unroll
    for (int k4 = 0; k4 < F_IN / 4; ++k4) {
        const float4 xv = xr[k4];   // wave-uniform load
        acc = fmaf(xv.x, w_lds[k4 * 4 + 0][lane], acc);
        acc = fmaf(xv.y, w_lds[k4 * 4 + 1][lane], acc);
        acc = fmaf(xv.z, w_lds[k4 * 4 + 2][lane], acc);
        acc = fmaf(xv.w, w_lds[k4 * 4 + 3][lane], acc);
    }
    h[(size_t)row * F_OUT + lane] = acc;
}

// ---------------- CSR build ----------------
__global__ __launch_bounds__(256) void hist_kernel(const int* __restrict__ ei,
                                                   unsigned* __restrict__ cnt, int E) {
    const int e = blockIdx.x * 256 + threadIdx.x;
    if (e < E) atomicAdd(&cnt[ei[e]], 1u);
}

__global__ __launch_bounds__(256) void scan1(const unsigned* __restrict__ cnt,
                                             unsigned* __restrict__ bsum, int n) {
    __shared__ unsigned lds[256];
    const int t = threadIdx.x;
    const int base = blockIdx.x * 2048 + t * 8;
    unsigned s = 0;
#pragma unroll
    for (int i = 0; i < 8; ++i) { const int idx = base + i; if (idx < n) s += cnt[idx]; }
    lds[t] = s; __syncthreads();
    for (int st = 128; st > 0; st >>= 1) {
        if (t < st) lds[t] += lds[t + st];
        __syncthreads();
    }
    if (t == 0) bsum[blockIdx.x] = lds[0];
}

__global__ __launch_bounds__(128) void scan2(unsigned* __restrict__ bsum,
                                             unsigned* __restrict__ off, int nb, int n) {
    __shared__ unsigned lds[128];
    const int t = threadIdx.x;
    if (t < nb) lds[t] = bsum[t];
    __syncthreads();
    if (t == 0) {
        unsigned run = 0;
        for (int i = 0; i < nb; ++i) { const unsigned v = lds[i]; lds[i] = run; run += v; }
        off[n] = run;
    }
    __syncthreads();
    if (t < nb) bsum[t] = lds[t];
}

__global__ __launch_bounds__(256) void scan3(const unsigned* __restrict__ cnt,
                                             const unsigned* __restrict__ bsum,
                                             unsigned* __restrict__ off,
                                             unsigned* __restrict__ cursor, int n) {
    __shared__ unsigned lds[256];
    const int t = threadIdx.x;
    const int base = blockIdx.x * 2048 + t * 8;
    unsigned v[8]; unsigned s = 0;
#pragma unroll
    for (int i = 0; i < 8; ++i) { const int idx = base + i; v[i] = (idx < n) ? cnt[idx] : 0u; s += v[i]; }
    lds[t] = s; __syncthreads();
    for (int st = 1; st < 256; st <<= 1) {
        const unsigned add = (t >= st) ? lds[t - st] : 0u;
        __syncthreads();
        lds[t] += add;
        __syncthreads();
    }
    unsigned excl = (t > 0 ? lds[t - 1] : 0u) + bsum[blockIdx.x];
#pragma unroll
    for (int i = 0; i < 8; ++i) {
        const int idx = base + i;
        if (idx < n) { off[idx] = excl; cursor[idx] = excl; excl += v[i]; }
    }
}

__global__ __launch_bounds__(256) void scatter_kernel(const int* __restrict__ ei,
                                                      unsigned* __restrict__ cursor,
                                                      int* __restrict__ sdst, int E) {
    const int e = blockIdx.x * 256 + threadIdx.x;
    if (e >= E) return;
    const int s = ei[e];
    const int d = ei[E + e];
    const unsigned pos = atomicAdd(&cursor[s], 1u);
    sdst[pos] = d;
}

// ---------------- Fused per-node score + aggregate + divide (4-edge pipelined) ----------------
__global__ __launch_bounds__(256) void node_kernel(const unsigned* __restrict__ off,
                                                   const int* __restrict__ sdst,
                                                   const float* __restrict__ h,
                                                   const float* __restrict__ a,
                                                   float* __restrict__ out, int N) {
    const int lane = threadIdx.x & 63;
    int node = (int)((blockIdx.x * 256u + threadIdx.x) >> 6);
    if (node >= N) return;
    node = __builtin_amdgcn_readfirstlane(node);

    const float a0 = a[lane];
    const float a1 = a[64 + lane];
    const float a2 = a[128 + lane];
    const float a3 = a[192 + lane];

    const int beg = (int)__builtin_amdgcn_readfirstlane((int)off[node]);
    const int end = (int)__builtin_amdgcn_readfirstlane((int)off[node + 1]);

    const float hs = h[(size_t)node * F_OUT + lane];

    // cs = full-wave sum of hs*a0 (per-node constant, added AFTER each edge reduce)
    float cs = hs * a0;
#pragma unroll
    for (int m = 1; m < 64; m <<= 1) cs += __shfl_xor(cs, m);

    float acc = 0.f, rsum = 0.f;

    float g0 = 0.f, g1 = 0.f, g2 = 0.f, g3 = 0.f;
    float t0, t1, t2, t3;

    if (beg < end) {
        const int d0 = sdst[beg];
        const int d1 = (beg + 1 < end) ? sdst[beg + 1] : d0;
        const int d2 = (beg + 2 < end) ? sdst[beg + 2] : d0;
        const int d3 = (beg + 3 < end) ? sdst[beg + 3] : d0;
        g0 = h[(size_t)d0 * F_OUT + lane];
        g1 = h[(size_t)d1 * F_OUT + lane];
        g2 = h[(size_t)d2 * F_OUT + lane];
        g3 = h[(size_t)d3 * F_OUT + lane];
    }

    for (int base = beg; base < end; base += 4) {
        const int nb = base + 4;
        if (nb < end) {  // prefetch next chunk under current compute
            const int d0 = sdst[nb];
            const int d1 = (nb + 1 < end) ? sdst[nb + 1] : d0;
            const int d2 = (nb + 2 < end) ? sdst[nb + 2] : d0;
            const int d3 = (nb + 3 < end) ? sdst[nb + 3] : d0;
            t0 = h[(size_t)d0 * F_OUT + lane];
            t1 = h[(size_t)d1 * F_OUT + lane];
            t2 = h[(size_t)d2 * F_OUT + lane];
            t3 = h[(size_t)d3 * F_OUT + lane];
        } else {
            t0 = t1 = t2 = t3 = 0.f;
        }

        float s0 = edge_part(hs, g0, a1, a2, a3);
        float s1 = edge_part(hs, g1, a1, a2, a3);
        float s2 = edge_part(hs, g2, a1, a2, a3);
        float s3 = edge_part(hs, g3, a1, a2, a3);
#pragma unroll
        for (int m = 1; m < 64; m <<= 1) {   // 4 independent butterfly chains
            s0 += __shfl_xor(s0, m);
            s1 += __shfl_xor(s1, m);
            s2 += __shfl_xor(s2, m);
            s3 += __shfl_xor(s3, m);
        }

        const float e0 = __expf(-leaky(cs + s0));
        const float e1 = (base + 1 < end) ? __expf(-leaky(cs + s1)) : 0.f;
        const float e2 = (base + 2 < end) ? __expf(-leaky(cs + s2)) : 0.f;
        const float e3 = (base + 3 < end) ? __expf(-leaky(cs + s3)) : 0.f;

        acc = fmaf(e0, g0, acc);
        acc = fmaf(e1, g1, acc);
        acc = fmaf(e2, g2, acc);
        acc = fmaf(e3, g3, acc);
        rsum += (e0 + e1) + (e2 + e3);

        g0 = t0; g1 = t1; g2 = t2; g3 = t3;
    }

    out[(size_t)node * F_OUT + lane] = acc / (rsum + 1e-16f);
}

// ---------------- Fallback path (atomic version) ----------------
__global__ __launch_bounds__(256) void edge_kernel(const int* __restrict__ ei,
                                                   const float* __restrict__ h,
                                                   const float* __restrict__ a,
                                                   float* __restrict__ hprime,
                                                   float* __restrict__ rowsum,
                                                   int E) {
    const int lane = threadIdx.x & 63;
    const int wave = (int)((blockIdx.x * blockDim.x + threadIdx.x) >> 6);
    const int nwaves = (int)((gridDim.x * blockDim.x) >> 6);
    const float a0 = a[lane], a1 = a[64 + lane], a2 = a[128 + lane], a3 = a[192 + lane];
    for (int e = wave; e < E; e += nwaves) {
        const int s = ei[e];
        const int d = ei[E + e];
        const float hs = h[(size_t)s * F_OUT + lane];
        const float hd = h[(size_t)d * F_OUT + lane];
        float part = hs * a0 + edge_part(hs, hd, a1, a2, a3);
#pragma unroll
        for (int m = 1; m < 64; m <<= 1) part += __shfl_xor(part, m);
        const float ee = __expf(-leaky(part));
        atomicAdd(&hprime[(size_t)s * F_OUT + lane], ee * hd);
        if (lane == 0) atomicAdd(&rowsum[s], ee);
    }
}

__global__ __launch_bounds__(256) void finalize(float* __restrict__ out,
                                                const float* __restrict__ rowsum,
                                                int total) {
    const int i = blockIdx.x * blockDim.x + threadIdx.x;
    if (i < total) out[i] = out[i] / (rowsum[i >> 6] + 1e-16f);
}

static inline size_t align_up(size_t v, size_t a) { return (v + a - 1) & ~(a - 1); }

extern "C" void kernel_launch(void* const* d_in, const int* in_sizes, int n_in,
                              void* d_out, int out_size, void* d_ws, size_t ws_size,
                              hipStream_t stream) {
    const float* x  = (const float*)d_in[0];
    const int*   ei = (const int*)d_in[1];
    const float* W  = (const float*)d_in[2];
    const float* a  = (const float*)d_in[3];

    const int N = in_sizes[0] / F_IN;
    const int E = in_sizes[1] / 2;
    float* out = (float*)d_out;

    char* ws = (char*)d_ws;
    size_t off_b    = align_up((size_t)N * F_OUT * 4, 256);            // h
    size_t cursor_b = off_b + align_up(((size_t)N + 1) * 4, 256);      // off
    size_t sdst_b   = cursor_b + align_up((size_t)N * 4, 256);         // cursor
    size_t cnt_b    = sdst_b + align_up((size_t)E * 4 + 64, 256);      // sdst (+pad)
    size_t bsum_b   = cnt_b + align_up((size_t)N * 4, 256);            // cnt
    size_t need     = bsum_b + align_up(4096, 256);                    // bsum

    float* h = (float*)ws;

    if (ws_size >= need) {
        unsigned* off    = (unsigned*)(ws + off_b);
        unsigned* cursor = (unsigned*)(ws + cursor_b);
        int*      sdst   = (int*)(ws + sdst_b);
        unsigned* cnt    = (unsigned*)(ws + cnt_b);
        unsigned* bsum   = (unsigned*)(ws + bsum_b);

        const int nb = (N + 2047) / 2048;

        hipMemsetAsync(cnt, 0, (size_t)N * 4, stream);
        gemm_xw<<<(N + 3) / 4, 256, 0, stream>>>(x, W, h, N);
        hist_kernel<<<(E + 255) / 256, 256, 0, stream>>>(ei, cnt, E);
        scan1<<<nb, 256, 0, stream>>>(cnt, bsum, N);
        scan2<<<1, 128, 0, stream>>>(bsum, off, nb, N);
        scan3<<<nb, 256, 0, stream>>>(cnt, bsum, off, cursor, N);
        scatter_kernel<<<(E + 255) / 256, 256, 0, stream>>>(ei, cursor, sdst, E);
        node_kernel<<<((size_t)N * 64 + 255) / 256, 256, 0, stream>>>(off, sdst, h, a, out, N);
    } else {
        float* rowsum = (float*)(ws + off_b);
        hipMemsetAsync(d_out, 0, (size_t)N * F_OUT * sizeof(float), stream);
        hipMemsetAsync(rowsum, 0, (size_t)N * sizeof(float), stream);
        gemm_xw<<<(N + 3) / 4, 256, 0, stream>>>(x, W, h, N);
        edge_kernel<<<2048, 256, 0, stream>>>(ei, h, a, out, rowsum, E);
        finalize<<<((size_t)N * F_OUT + 255) / 256, 256, 0, stream>>>(out, rowsum, N * F_OUT);
    }
}

// Round 4
// 342.343 us; speedup vs baseline: 1.5653x; 1.2703x over previous
//
#include <hip/hip_runtime.h>

#define F_IN 128
#define F_OUT 64

__device__ __forceinline__ float leaky(float v) {
    return fmaf(0.495f, fabsf(v), 0.505f * v);   // == leaky_relu(v, 0.01)
}

__device__ __forceinline__ float edge_part(float hs, float hd, float a1, float a2, float a3) {
    float p = hd * a1;
    p = fmaf(leaky(hs + hd), a2, p);
    p = fmaf(leaky(hs - hd), a3, p);
    return p;
}

// Full-wave (64-lane) sum via DPP — no DS-pipe traffic. Result uniform (SGPR).
__device__ __forceinline__ float wave_sum(float v) {
    v += __builtin_bit_cast(float, __builtin_amdgcn_update_dpp(0, __builtin_bit_cast(int, v), 0x111, 0xf, 0xf, true)); // row_shr:1
    v += __builtin_bit_cast(float, __builtin_amdgcn_update_dpp(0, __builtin_bit_cast(int, v), 0x112, 0xf, 0xf, true)); // row_shr:2
    v += __builtin_bit_cast(float, __builtin_amdgcn_update_dpp(0, __builtin_bit_cast(int, v), 0x114, 0xf, 0xe, true)); // row_shr:4
    v += __builtin_bit_cast(float, __builtin_amdgcn_update_dpp(0, __builtin_bit_cast(int, v), 0x118, 0xf, 0xc, true)); // row_shr:8
    v += __builtin_bit_cast(float, __builtin_amdgcn_update_dpp(0, __builtin_bit_cast(int, v), 0x142, 0xa, 0xf, true)); // row_bcast:15
    v += __builtin_bit_cast(float, __builtin_amdgcn_update_dpp(0, __builtin_bit_cast(int, v), 0x143, 0xc, 0xf, true)); // row_bcast:31
    return __builtin_bit_cast(float, __builtin_amdgcn_readlane(__builtin_bit_cast(int, v), 63));
}

// ---------------- Kernel 1: h = x @ W ----------------
// Block = 256 threads computes 128 rows x 64 cols.
// Thread t: col-group cg = t&15 (4 cols), row-slot rs = t>>4 (8 rows).
// W staged in LDS (b128 reads, conflict-free); x read straight from global
// (16 lanes share each 16B line -> coalescer dedups; x streamed once).
__global__ __launch_bounds__(256) void gemm_xw(const float* __restrict__ x,
                                               const float* __restrict__ W,
                                               float* __restrict__ h, int N) {
    __shared__ float w_lds[F_IN][F_OUT];   // 32 KB
    {
        const float4* Wv = (const float4*)W;
        float4* wl = (float4*)w_lds;
        for (int i = threadIdx.x; i < F_IN * F_OUT / 4; i += 256) wl[i] = Wv[i];
    }
    __syncthreads();

    const int cg = threadIdx.x & 15;         // col group (4 cols)
    const int rs = threadIdx.x >> 4;         // row slot (8 rows)
    const int row0 = blockIdx.x * 128 + rs * 8;

    float4 acc[8];
#pragma unroll
    for (int i = 0; i < 8; ++i) acc[i] = make_float4(0.f, 0.f, 0.f, 0.f);

    for (int k4 = 0; k4 < F_IN / 4; ++k4) {
        float4 wv[4];
#pragma unroll
        for (int kk = 0; kk < 4; ++kk)
            wv[kk] = *(const float4*)&w_lds[k4 * 4 + kk][cg * 4];

        float4 xv[8];
#pragma unroll
        for (int i = 0; i < 8; ++i) {
            int r = row0 + i; if (r >= N) r = N - 1;      // clamp (stores guarded)
            xv[i] = *(const float4*)(x + (size_t)r * F_IN + k4 * 4);
        }

#pragma unroll
        for (int i = 0; i < 8; ++i) {
            acc[i].x = fmaf(xv[i].x, wv[0].x, acc[i].x);
            acc[i].y = fmaf(xv[i].x, wv[0].y, acc[i].y);
            acc[i].z = fmaf(xv[i].x, wv[0].z, acc[i].z);
            acc[i].w = fmaf(xv[i].x, wv[0].w, acc[i].w);
            acc[i].x = fmaf(xv[i].y, wv[1].x, acc[i].x);
            acc[i].y = fmaf(xv[i].y, wv[1].y, acc[i].y);
            acc[i].z = fmaf(xv[i].y, wv[1].z, acc[i].z);
            acc[i].w = fmaf(xv[i].y, wv[1].w, acc[i].w);
            acc[i].x = fmaf(xv[i].z, wv[2].x, acc[i].x);
            acc[i].y = fmaf(xv[i].z, wv[2].y, acc[i].y);
            acc[i].z = fmaf(xv[i].z, wv[2].z, acc[i].z);
            acc[i].w = fmaf(xv[i].z, wv[2].w, acc[i].w);
            acc[i].x = fmaf(xv[i].w, wv[3].x, acc[i].x);
            acc[i].y = fmaf(xv[i].w, wv[3].y, acc[i].y);
            acc[i].z = fmaf(xv[i].w, wv[3].z, acc[i].z);
            acc[i].w = fmaf(xv[i].w, wv[3].w, acc[i].w);
        }
    }

#pragma unroll
    for (int i = 0; i < 8; ++i) {
        const int r = row0 + i;
        if (r < N) *(float4*)(h + (size_t)r * F_OUT + cg * 4) = acc[i];
    }
}

// ---------------- CSR build ----------------
__global__ __launch_bounds__(256) void hist_kernel(const int* __restrict__ ei,
                                                   unsigned* __restrict__ cnt, int E) {
    const int e = blockIdx.x * 256 + threadIdx.x;
    if (e < E) atomicAdd(&cnt[ei[e]], 1u);
}

__global__ __launch_bounds__(256) void scan1(const unsigned* __restrict__ cnt,
                                             unsigned* __restrict__ bsum, int n) {
    __shared__ unsigned lds[256];
    const int t = threadIdx.x;
    const int base = blockIdx.x * 2048 + t * 8;
    unsigned s = 0;
#pragma unroll
    for (int i = 0; i < 8; ++i) { const int idx = base + i; if (idx < n) s += cnt[idx]; }
    lds[t] = s; __syncthreads();
    for (int st = 128; st > 0; st >>= 1) {
        if (t < st) lds[t] += lds[t + st];
        __syncthreads();
    }
    if (t == 0) bsum[blockIdx.x] = lds[0];
}

__global__ __launch_bounds__(128) void scan2(unsigned* __restrict__ bsum,
                                             unsigned* __restrict__ off, int nb, int n) {
    __shared__ unsigned lds[128];
    const int t = threadIdx.x;
    if (t < nb) lds[t] = bsum[t];
    __syncthreads();
    if (t == 0) {
        unsigned run = 0;
        for (int i = 0; i < nb; ++i) { const unsigned v = lds[i]; lds[i] = run; run += v; }
        off[n] = run;
    }
    __syncthreads();
    if (t < nb) bsum[t] = lds[t];
}

__global__ __launch_bounds__(256) void scan3(const unsigned* __restrict__ cnt,
                                             const unsigned* __restrict__ bsum,
                                             unsigned* __restrict__ off,
                                             unsigned* __restrict__ cursor, int n) {
    __shared__ unsigned lds[256];
    const int t = threadIdx.x;
    const int base = blockIdx.x * 2048 + t * 8;
    unsigned v[8]; unsigned s = 0;
#pragma unroll
    for (int i = 0; i < 8; ++i) { const int idx = base + i; v[i] = (idx < n) ? cnt[idx] : 0u; s += v[i]; }
    lds[t] = s; __syncthreads();
    for (int st = 1; st < 256; st <<= 1) {
        const unsigned add = (t >= st) ? lds[t - st] : 0u;
        __syncthreads();
        lds[t] += add;
        __syncthreads();
    }
    unsigned excl = (t > 0 ? lds[t - 1] : 0u) + bsum[blockIdx.x];
#pragma unroll
    for (int i = 0; i < 8; ++i) {
        const int idx = base + i;
        if (idx < n) { off[idx] = excl; cursor[idx] = excl; excl += v[i]; }
    }
}

__global__ __launch_bounds__(256) void scatter_kernel(const int* __restrict__ ei,
                                                      unsigned* __restrict__ cursor,
                                                      int* __restrict__ sdst, int E) {
    const int e = blockIdx.x * 256 + threadIdx.x;
    if (e >= E) return;
    const int s = ei[e];
    const int d = ei[E + e];
    const unsigned pos = atomicAdd(&cursor[s], 1u);
    sdst[pos] = d;
}

// ---------------- Fused per-node score + aggregate + divide ----------------
__global__ __launch_bounds__(256) void node_kernel(const unsigned* __restrict__ off,
                                                   const int* __restrict__ sdst,
                                                   const float* __restrict__ h,
                                                   const float* __restrict__ a,
                                                   float* __restrict__ out, int N) {
    const int lane = threadIdx.x & 63;
    int node = (int)((blockIdx.x * 256u + threadIdx.x) >> 6);
    if (node >= N) return;
    node = __builtin_amdgcn_readfirstlane(node);

    const float a0 = a[lane];
    const float a1 = a[64 + lane];
    const float a2 = a[128 + lane];
    const float a3 = a[192 + lane];

    const int beg = (int)__builtin_amdgcn_readfirstlane((int)off[node]);
    const int end = (int)__builtin_amdgcn_readfirstlane((int)off[node + 1]);

    const float hs = h[(size_t)node * F_OUT + lane];
    const float cs = wave_sum(hs * a0);   // per-node constant part of the score

    float acc = 0.f, rsum = 0.f;
    float g0 = 0.f, g1 = 0.f, g2 = 0.f, g3 = 0.f;
    float t0, t1, t2, t3;

    if (beg < end) {
        const int d0 = sdst[beg];
        const int d1 = (beg + 1 < end) ? sdst[beg + 1] : d0;
        const int d2 = (beg + 2 < end) ? sdst[beg + 2] : d0;
        const int d3 = (beg + 3 < end) ? sdst[beg + 3] : d0;
        g0 = h[(size_t)d0 * F_OUT + lane];
        g1 = h[(size_t)d1 * F_OUT + lane];
        g2 = h[(size_t)d2 * F_OUT + lane];
        g3 = h[(size_t)d3 * F_OUT + lane];
    }

    for (int base = beg; base < end; base += 4) {
        const int nb = base + 4;
        if (nb < end) {  // prefetch next chunk under current compute
            const int d0 = sdst[nb];
            const int d1 = (nb + 1 < end) ? sdst[nb + 1] : d0;
            const int d2 = (nb + 2 < end) ? sdst[nb + 2] : d0;
            const int d3 = (nb + 3 < end) ? sdst[nb + 3] : d0;
            t0 = h[(size_t)d0 * F_OUT + lane];
            t1 = h[(size_t)d1 * F_OUT + lane];
            t2 = h[(size_t)d2 * F_OUT + lane];
            t3 = h[(size_t)d3 * F_OUT + lane];
        } else {
            t0 = t1 = t2 = t3 = 0.f;
        }

        // four independent DPP reduction chains (pure VALU, no DS)
        const float s0 = wave_sum(edge_part(hs, g0, a1, a2, a3));
        const float s1 = wave_sum(edge_part(hs, g1, a1, a2, a3));
        const float s2 = wave_sum(edge_part(hs, g2, a1, a2, a3));
        const float s3 = wave_sum(edge_part(hs, g3, a1, a2, a3));

        const float e0 = __expf(-leaky(cs + s0));
        const float e1 = (base + 1 < end) ? __expf(-leaky(cs + s1)) : 0.f;
        const float e2 = (base + 2 < end) ? __expf(-leaky(cs + s2)) : 0.f;
        const float e3 = (base + 3 < end) ? __expf(-leaky(cs + s3)) : 0.f;

        acc = fmaf(e0, g0, acc);
        acc = fmaf(e1, g1, acc);
        acc = fmaf(e2, g2, acc);
        acc = fmaf(e3, g3, acc);
        rsum += (e0 + e1) + (e2 + e3);

        g0 = t0; g1 = t1; g2 = t2; g3 = t3;
    }

    out[(size_t)node * F_OUT + lane] = acc / (rsum + 1e-16f);
}

// ---------------- Fallback path (atomic version) ----------------
__global__ __launch_bounds__(256) void edge_kernel(const int* __restrict__ ei,
                                                   const float* __restrict__ h,
                                                   const float* __restrict__ a,
                                                   float* __restrict__ hprime,
                                                   float* __restrict__ rowsum,
                                                   int E) {
    const int lane = threadIdx.x & 63;
    const int wave = (int)((blockIdx.x * blockDim.x + threadIdx.x) >> 6);
    const int nwaves = (int)((gridDim.x * blockDim.x) >> 6);
    const float a0 = a[lane], a1 = a[64 + lane], a2 = a[128 + lane], a3 = a[192 + lane];
    for (int e = wave; e < E; e += nwaves) {
        const int s = ei[e];
        const int d = ei[E + e];
        const float hs = h[(size_t)s * F_OUT + lane];
        const float hd = h[(size_t)d * F_OUT + lane];
        const float part = wave_sum(hs * a0 + edge_part(hs, hd, a1, a2, a3));
        const float ee = __expf(-leaky(part));
        atomicAdd(&hprime[(size_t)s * F_OUT + lane], ee * hd);
        if (lane == 0) atomicAdd(&rowsum[s], ee);
    }
}

__global__ __launch_bounds__(256) void finalize(float* __restrict__ out,
                                                const float* __restrict__ rowsum,
                                                int total) {
    const int i = blockIdx.x * blockDim.x + threadIdx.x;
    if (i < total) out[i] = out[i] / (rowsum[i >> 6] + 1e-16f);
}

static inline size_t align_up(size_t v, size_t a) { return (v + a - 1) & ~(a - 1); }

extern "C" void kernel_launch(void* const* d_in, const int* in_sizes, int n_in,
                              void* d_out, int out_size, void* d_ws, size_t ws_size,
                              hipStream_t stream) {
    const float* x  = (const float*)d_in[0];
    const int*   ei = (const int*)d_in[1];
    const float* W  = (const float*)d_in[2];
    const float* a  = (const float*)d_in[3];

    const int N = in_sizes[0] / F_IN;
    const int E = in_sizes[1] / 2;
    float* out = (float*)d_out;

    char* ws = (char*)d_ws;
    size_t off_b    = align_up((size_t)N * F_OUT * 4, 256);            // h
    size_t cursor_b = off_b + align_up(((size_t)N + 1) * 4, 256);      // off
    size_t sdst_b   = cursor_b + align_up((size_t)N * 4, 256);         // cursor
    size_t cnt_b    = sdst_b + align_up((size_t)E * 4 + 64, 256);      // sdst (+pad)
    size_t bsum_b   = cnt_b + align_up((size_t)N * 4, 256);            // cnt
    size_t need     = bsum_b + align_up(4096, 256);                    // bsum

    float* h = (float*)ws;

    if (ws_size >= need) {
        unsigned* off    = (unsigned*)(ws + off_b);
        unsigned* cursor = (unsigned*)(ws + cursor_b);
        int*      sdst   = (int*)(ws + sdst_b);
        unsigned* cnt    = (unsigned*)(ws + cnt_b);
        unsigned* bsum   = (unsigned*)(ws + bsum_b);

        const int nb = (N + 2047) / 2048;

        hipMemsetAsync(cnt, 0, (size_t)N * 4, stream);
        gemm_xw<<<(N + 127) / 128, 256, 0, stream>>>(x, W, h, N);
        hist_kernel<<<(E + 255) / 256, 256, 0, stream>>>(ei, cnt, E);
        scan1<<<nb, 256, 0, stream>>>(cnt, bsum, N);
        scan2<<<1, 128, 0, stream>>>(bsum, off, nb, N);
        scan3<<<nb, 256, 0, stream>>>(cnt, bsum, off, cursor, N);
        scatter_kernel<<<(E + 255) / 256, 256, 0, stream>>>(ei, cursor, sdst, E);
        node_kernel<<<((size_t)N * 64 + 255) / 256, 256, 0, stream>>>(off, sdst, h, a, out, N);
    } else {
        float* rowsum = (float*)(ws + off_b);
        hipMemsetAsync(d_out, 0, (size_t)N * F_OUT * sizeof(float), stream);
        hipMemsetAsync(rowsum, 0, (size_t)N * sizeof(float), stream);
        gemm_xw<<<(N + 127) / 128, 256, 0, stream>>>(x, W, h, N);
        edge_kernel<<<2048, 256, 0, stream>>>(ei, h, a, out, rowsum, E);
        finalize<<<((size_t)N * F_OUT + 255) / 256, 256, 0, stream>>>(out, rowsum, N * F_OUT);
    }
}

// Round 5
// 217.220 us; speedup vs baseline: 2.4670x; 1.5760x over previous
//
#include <hip/hip_runtime.h>

#define F_IN 128
#define F_OUT 64
#define BIN_TILE 2048
#define BIN_CAP 24576   // LDS staging capacity per bucket (96 KB); overflow handled via global tail

__device__ __forceinline__ float leaky(float v) {
    return fmaf(0.495f, fabsf(v), 0.505f * v);   // == leaky_relu(v, 0.01)
}

__device__ __forceinline__ float edge_part(float hs, float hd, float a1, float a2, float a3) {
    float p = hd * a1;
    p = fmaf(leaky(hs + hd), a2, p);
    p = fmaf(leaky(hs - hd), a3, p);
    return p;
}

// Full-wave (64-lane) sum via DPP — no DS-pipe traffic. Result uniform.
__device__ __forceinline__ float wave_sum(float v) {
    v += __builtin_bit_cast(float, __builtin_amdgcn_update_dpp(0, __builtin_bit_cast(int, v), 0x111, 0xf, 0xf, true)); // row_shr:1
    v += __builtin_bit_cast(float, __builtin_amdgcn_update_dpp(0, __builtin_bit_cast(int, v), 0x112, 0xf, 0xf, true)); // row_shr:2
    v += __builtin_bit_cast(float, __builtin_amdgcn_update_dpp(0, __builtin_bit_cast(int, v), 0x114, 0xf, 0xe, true)); // row_shr:4
    v += __builtin_bit_cast(float, __builtin_amdgcn_update_dpp(0, __builtin_bit_cast(int, v), 0x118, 0xf, 0xc, true)); // row_shr:8
    v += __builtin_bit_cast(float, __builtin_amdgcn_update_dpp(0, __builtin_bit_cast(int, v), 0x142, 0xa, 0xf, true)); // row_bcast:15
    v += __builtin_bit_cast(float, __builtin_amdgcn_update_dpp(0, __builtin_bit_cast(int, v), 0x143, 0xc, 0xf, true)); // row_bcast:31
    return __builtin_bit_cast(float, __builtin_amdgcn_readlane(__builtin_bit_cast(int, v), 63));
}

// ---------------- Kernel 1: h = x @ W (128 rows x 64 cols per block) ----------------
__global__ __launch_bounds__(256) void gemm_xw(const float* __restrict__ x,
                                               const float* __restrict__ W,
                                               float* __restrict__ h, int N) {
    __shared__ float w_lds[F_IN][F_OUT];   // 32 KB
    {
        const float4* Wv = (const float4*)W;
        float4* wl = (float4*)w_lds;
        for (int i = threadIdx.x; i < F_IN * F_OUT / 4; i += 256) wl[i] = Wv[i];
    }
    __syncthreads();

    const int cg = threadIdx.x & 15;
    const int rs = threadIdx.x >> 4;
    const int row0 = blockIdx.x * 128 + rs * 8;

    float4 acc[8];
#pragma unroll
    for (int i = 0; i < 8; ++i) acc[i] = make_float4(0.f, 0.f, 0.f, 0.f);

    for (int k4 = 0; k4 < F_IN / 4; ++k4) {
        float4 wv[4];
#pragma unroll
        for (int kk = 0; kk < 4; ++kk)
            wv[kk] = *(const float4*)&w_lds[k4 * 4 + kk][cg * 4];

        float4 xv[8];
#pragma unroll
        for (int i = 0; i < 8; ++i) {
            int r = row0 + i; if (r >= N) r = N - 1;
            xv[i] = *(const float4*)(x + (size_t)r * F_IN + k4 * 4);
        }
#pragma unroll
        for (int i = 0; i < 8; ++i) {
            acc[i].x = fmaf(xv[i].x, wv[0].x, acc[i].x);
            acc[i].y = fmaf(xv[i].x, wv[0].y, acc[i].y);
            acc[i].z = fmaf(xv[i].x, wv[0].z, acc[i].z);
            acc[i].w = fmaf(xv[i].x, wv[0].w, acc[i].w);
            acc[i].x = fmaf(xv[i].y, wv[1].x, acc[i].x);
            acc[i].y = fmaf(xv[i].y, wv[1].y, acc[i].y);
            acc[i].z = fmaf(xv[i].y, wv[1].z, acc[i].z);
            acc[i].w = fmaf(xv[i].y, wv[1].w, acc[i].w);
            acc[i].x = fmaf(xv[i].z, wv[2].x, acc[i].x);
            acc[i].y = fmaf(xv[i].z, wv[2].y, acc[i].y);
            acc[i].z = fmaf(xv[i].z, wv[2].z, acc[i].z);
            acc[i].w = fmaf(xv[i].z, wv[2].w, acc[i].w);
            acc[i].x = fmaf(xv[i].w, wv[3].x, acc[i].x);
            acc[i].y = fmaf(xv[i].w, wv[3].y, acc[i].y);
            acc[i].z = fmaf(xv[i].w, wv[3].z, acc[i].z);
            acc[i].w = fmaf(xv[i].w, wv[3].w, acc[i].w);
        }
    }
#pragma unroll
    for (int i = 0; i < 8; ++i) {
        const int r = row0 + i;
        if (r < N) *(float4*)(h + (size_t)r * F_OUT + cg * 4) = acc[i];
    }
}

// ---------------- 2-level binned CSR build ----------------
// bucket = src >> 10 (1024 nodes per bucket). Packed payload: (s_local<<17)|d.
__global__ __launch_bounds__(256) void bucket_count(const int* __restrict__ ei,
                                                    unsigned* __restrict__ bcnt, int E, int NB) {
    __shared__ unsigned hc[1024];
    const int t = threadIdx.x;
    for (int i = t; i < NB; i += 256) hc[i] = 0;
    __syncthreads();
    const int base = blockIdx.x * BIN_TILE;
#pragma unroll
    for (int i = 0; i < 8; ++i) {
        const int e = base + i * 256 + t;
        if (e < E) atomicAdd(&hc[((unsigned)ei[e]) >> 10], 1u);
    }
    __syncthreads();
    for (int i = t; i < NB; i += 256)
        if (hc[i]) atomicAdd(&bcnt[i], hc[i]);
}

__global__ __launch_bounds__(256) void scan_buckets(const unsigned* __restrict__ bcnt,
                                                    unsigned* __restrict__ bbase,
                                                    unsigned* __restrict__ gcur, int NB) {
    __shared__ unsigned v[1024];
    __shared__ unsigned ts[256];
    const int t = threadIdx.x;
    for (int i = t; i < 1024; i += 256) v[i] = (i < NB) ? bcnt[i] : 0u;
    __syncthreads();
    unsigned s = 0;
#pragma unroll
    for (int j = 0; j < 4; ++j) s += v[t * 4 + j];
    ts[t] = s;
    __syncthreads();
    for (int st = 1; st < 256; st <<= 1) {
        const unsigned add = (t >= st) ? ts[t - st] : 0u;
        __syncthreads();
        ts[t] += add;
        __syncthreads();
    }
    unsigned run = (t > 0) ? ts[t - 1] : 0u;
#pragma unroll
    for (int j = 0; j < 4; ++j) {
        const int i = t * 4 + j;
        const unsigned c = v[i];
        if (i < NB) { bbase[i] = run; gcur[i] = run; }
        run += c;
    }
}

__global__ __launch_bounds__(256) void binA(const int* __restrict__ ei,
                                            unsigned* __restrict__ gcur,
                                            unsigned* __restrict__ binned, int E, int NB) {
    __shared__ unsigned lcnt[1024];
    __shared__ unsigned lbase[1024];
    const int t = threadIdx.x;
    for (int i = t; i < NB; i += 256) lcnt[i] = 0;
    __syncthreads();
    const int base = blockIdx.x * BIN_TILE;
    unsigned pk[8], bk[8], rk[8];
#pragma unroll
    for (int i = 0; i < 8; ++i) {
        const int e = base + i * 256 + t;
        if (e < E) {
            const unsigned s = (unsigned)ei[e];
            const unsigned d = (unsigned)ei[E + e];
            bk[i] = s >> 10;
            pk[i] = ((s & 1023u) << 17) | d;
            rk[i] = atomicAdd(&lcnt[bk[i]], 1u);
        }
    }
    __syncthreads();
    for (int i = t; i < NB; i += 256) {
        const unsigned c = lcnt[i];
        lbase[i] = c ? atomicAdd(&gcur[i], c) : 0u;
    }
    __syncthreads();
#pragma unroll
    for (int i = 0; i < 8; ++i) {
        const int e = base + i * 256 + t;
        if (e < E) binned[lbase[bk[i]] + rk[i]] = pk[i];
    }
}

// One block per bucket: per-node hist + scan in LDS -> off[]; scatter within
// a ~64 KB L2-resident window -> sdst[].
__global__ __launch_bounds__(256) void binB(const unsigned* __restrict__ binned,
                                            const unsigned* __restrict__ bbase,
                                            const unsigned* __restrict__ bcnt,
                                            unsigned* __restrict__ off,
                                            int* __restrict__ sdst, int N, int E, int NB) {
    __shared__ unsigned stg[BIN_CAP];    // 96 KB
    __shared__ unsigned ncnt[1024];
    __shared__ unsigned ts[256];
    const int b = blockIdx.x;
    const int t = threadIdx.x;
    const unsigned beg = bbase[b];
    const unsigned sz = bcnt[b];
    const unsigned ncap = (sz < (unsigned)BIN_CAP) ? sz : (unsigned)BIN_CAP;

    for (int i = t; i < 1024; i += 256) ncnt[i] = 0;
    for (unsigned i = t; i < ncap; i += 256) stg[i] = binned[beg + i];
    __syncthreads();

    for (unsigned i = t; i < sz; i += 256) {
        const unsigned p = (i < ncap) ? stg[i] : binned[beg + i];
        atomicAdd(&ncnt[p >> 17], 1u);
    }
    __syncthreads();

    // exclusive scan over 1024 node counts
    unsigned loc[4]; unsigned s = 0;
#pragma unroll
    for (int j = 0; j < 4; ++j) { loc[j] = ncnt[t * 4 + j]; s += loc[j]; }
    ts[t] = s;
    __syncthreads();
    for (int st = 1; st < 256; st <<= 1) {
        const unsigned add = (t >= st) ? ts[t - st] : 0u;
        __syncthreads();
        ts[t] += add;
        __syncthreads();
    }
    unsigned run = (t > 0) ? ts[t - 1] : 0u;
#pragma unroll
    for (int j = 0; j < 4; ++j) { const unsigned c = loc[j]; ncnt[t * 4 + j] = run; run += c; }
    __syncthreads();

    // write CSR offsets
    const int node0 = b << 10;
    for (int j = t; j < 1024; j += 256) {
        const int g = node0 + j;
        if (g < N) off[g] = beg + ncnt[j];
    }
    if (b == NB - 1 && t == 0) off[N] = (unsigned)E;
    __syncthreads();   // off reads ncnt; scatter below mutates it

    for (unsigned i = t; i < sz; i += 256) {
        const unsigned p = (i < ncap) ? stg[i] : binned[beg + i];
        const unsigned pos = atomicAdd(&ncnt[p >> 17], 1u);
        sdst[beg + pos] = (int)(p & 0x1FFFFu);
    }
}

// ---------------- Fused per-node score + aggregate + divide ----------------
__global__ __launch_bounds__(256) void node_kernel(const unsigned* __restrict__ off,
                                                   const int* __restrict__ sdst,
                                                   const float* __restrict__ h,
                                                   const float* __restrict__ a,
                                                   float* __restrict__ out, int N) {
    const int lane = threadIdx.x & 63;
    int node = (int)((blockIdx.x * 256u + threadIdx.x) >> 6);
    if (node >= N) return;
    node = __builtin_amdgcn_readfirstlane(node);

    const float a0 = a[lane];
    const float a1 = a[64 + lane];
    const float a2 = a[128 + lane];
    const float a3 = a[192 + lane];

    const int beg = (int)__builtin_amdgcn_readfirstlane((int)off[node]);
    const int end = (int)__builtin_amdgcn_readfirstlane((int)off[node + 1]);

    const float hs = h[(size_t)node * F_OUT + lane];
    const float cs = wave_sum(hs * a0);

    float acc = 0.f, rsum = 0.f;
    float g0 = 0.f, g1 = 0.f, g2 = 0.f, g3 = 0.f;
    float t0, t1, t2, t3;

    if (beg < end) {
        const int d0 = sdst[beg];
        const int d1 = (beg + 1 < end) ? sdst[beg + 1] : d0;
        const int d2 = (beg + 2 < end) ? sdst[beg + 2] : d0;
        const int d3 = (beg + 3 < end) ? sdst[beg + 3] : d0;
        g0 = h[(size_t)d0 * F_OUT + lane];
        g1 = h[(size_t)d1 * F_OUT + lane];
        g2 = h[(size_t)d2 * F_OUT + lane];
        g3 = h[(size_t)d3 * F_OUT + lane];
    }

    for (int base = beg; base < end; base += 4) {
        const int nb = base + 4;
        if (nb < end) {
            const int d0 = sdst[nb];
            const int d1 = (nb + 1 < end) ? sdst[nb + 1] : d0;
            const int d2 = (nb + 2 < end) ? sdst[nb + 2] : d0;
            const int d3 = (nb + 3 < end) ? sdst[nb + 3] : d0;
            t0 = h[(size_t)d0 * F_OUT + lane];
            t1 = h[(size_t)d1 * F_OUT + lane];
            t2 = h[(size_t)d2 * F_OUT + lane];
            t3 = h[(size_t)d3 * F_OUT + lane];
        } else {
            t0 = t1 = t2 = t3 = 0.f;
        }

        const float s0 = wave_sum(edge_part(hs, g0, a1, a2, a3));
        const float s1 = wave_sum(edge_part(hs, g1, a1, a2, a3));
        const float s2 = wave_sum(edge_part(hs, g2, a1, a2, a3));
        const float s3 = wave_sum(edge_part(hs, g3, a1, a2, a3));

        const float e0 = __expf(-leaky(cs + s0));
        const float e1 = (base + 1 < end) ? __expf(-leaky(cs + s1)) : 0.f;
        const float e2 = (base + 2 < end) ? __expf(-leaky(cs + s2)) : 0.f;
        const float e3 = (base + 3 < end) ? __expf(-leaky(cs + s3)) : 0.f;

        acc = fmaf(e0, g0, acc);
        acc = fmaf(e1, g1, acc);
        acc = fmaf(e2, g2, acc);
        acc = fmaf(e3, g3, acc);
        rsum += (e0 + e1) + (e2 + e3);

        g0 = t0; g1 = t1; g2 = t2; g3 = t3;
    }

    out[(size_t)node * F_OUT + lane] = acc / (rsum + 1e-16f);
}

// ---------------- Plan B: old CSR build (hist + scans + scatter) ----------------
__global__ __launch_bounds__(256) void hist_kernel(const int* __restrict__ ei,
                                                   unsigned* __restrict__ cnt, int E) {
    const int e = blockIdx.x * 256 + threadIdx.x;
    if (e < E) atomicAdd(&cnt[ei[e]], 1u);
}

__global__ __launch_bounds__(256) void scan1(const unsigned* __restrict__ cnt,
                                             unsigned* __restrict__ bsum, int n) {
    __shared__ unsigned lds[256];
    const int t = threadIdx.x;
    const int base = blockIdx.x * 2048 + t * 8;
    unsigned s = 0;
#pragma unroll
    for (int i = 0; i < 8; ++i) { const int idx = base + i; if (idx < n) s += cnt[idx]; }
    lds[t] = s; __syncthreads();
    for (int st = 128; st > 0; st >>= 1) {
        if (t < st) lds[t] += lds[t + st];
        __syncthreads();
    }
    if (t == 0) bsum[blockIdx.x] = lds[0];
}

__global__ __launch_bounds__(128) void scan2(unsigned* __restrict__ bsum,
                                             unsigned* __restrict__ off, int nb, int n) {
    __shared__ unsigned lds[128];
    const int t = threadIdx.x;
    if (t < nb) lds[t] = bsum[t];
    __syncthreads();
    if (t == 0) {
        unsigned run = 0;
        for (int i = 0; i < nb; ++i) { const unsigned v = lds[i]; lds[i] = run; run += v; }
        off[n] = run;
    }
    __syncthreads();
    if (t < nb) bsum[t] = lds[t];
}

__global__ __launch_bounds__(256) void scan3(const unsigned* __restrict__ cnt,
                                             const unsigned* __restrict__ bsum,
                                             unsigned* __restrict__ off,
                                             unsigned* __restrict__ cursor, int n) {
    __shared__ unsigned lds[256];
    const int t = threadIdx.x;
    const int base = blockIdx.x * 2048 + t * 8;
    unsigned v[8]; unsigned s = 0;
#pragma unroll
    for (int i = 0; i < 8; ++i) { const int idx = base + i; v[i] = (idx < n) ? cnt[idx] : 0u; s += v[i]; }
    lds[t] = s; __syncthreads();
    for (int st = 1; st < 256; st <<= 1) {
        const unsigned add = (t >= st) ? lds[t - st] : 0u;
        __syncthreads();
        lds[t] += add;
        __syncthreads();
    }
    unsigned excl = (t > 0 ? lds[t - 1] : 0u) + bsum[blockIdx.x];
#pragma unroll
    for (int i = 0; i < 8; ++i) {
        const int idx = base + i;
        if (idx < n) { off[idx] = excl; cursor[idx] = excl; excl += v[i]; }
    }
}

__global__ __launch_bounds__(256) void scatter_kernel(const int* __restrict__ ei,
                                                      unsigned* __restrict__ cursor,
                                                      int* __restrict__ sdst, int E) {
    const int e = blockIdx.x * 256 + threadIdx.x;
    if (e >= E) return;
    const int s = ei[e];
    const int d = ei[E + e];
    const unsigned pos = atomicAdd(&cursor[s], 1u);
    sdst[pos] = d;
}

// ---------------- Plan C: atomic fallback ----------------
__global__ __launch_bounds__(256) void edge_kernel(const int* __restrict__ ei,
                                                   const float* __restrict__ h,
                                                   const float* __restrict__ a,
                                                   float* __restrict__ hprime,
                                                   float* __restrict__ rowsum,
                                                   int E) {
    const int lane = threadIdx.x & 63;
    const int wave = (int)((blockIdx.x * blockDim.x + threadIdx.x) >> 6);
    const int nwaves = (int)((gridDim.x * blockDim.x) >> 6);
    const float a0 = a[lane], a1 = a[64 + lane], a2 = a[128 + lane], a3 = a[192 + lane];
    for (int e = wave; e < E; e += nwaves) {
        const int s = ei[e];
        const int d = ei[E + e];
        const float hs = h[(size_t)s * F_OUT + lane];
        const float hd = h[(size_t)d * F_OUT + lane];
        const float part = wave_sum(hs * a0 + edge_part(hs, hd, a1, a2, a3));
        const float ee = __expf(-leaky(part));
        atomicAdd(&hprime[(size_t)s * F_OUT + lane], ee * hd);
        if (lane == 0) atomicAdd(&rowsum[s], ee);
    }
}

__global__ __launch_bounds__(256) void finalize(float* __restrict__ out,
                                                const float* __restrict__ rowsum,
                                                int total) {
    const int i = blockIdx.x * blockDim.x + threadIdx.x;
    if (i < total) out[i] = out[i] / (rowsum[i >> 6] + 1e-16f);
}

static inline size_t align_up(size_t v, size_t a) { return (v + a - 1) & ~(a - 1); }

extern "C" void kernel_launch(void* const* d_in, const int* in_sizes, int n_in,
                              void* d_out, int out_size, void* d_ws, size_t ws_size,
                              hipStream_t stream) {
    const float* x  = (const float*)d_in[0];
    const int*   ei = (const int*)d_in[1];
    const float* W  = (const float*)d_in[2];
    const float* a  = (const float*)d_in[3];

    const int N = in_sizes[0] / F_IN;
    const int E = in_sizes[1] / 2;
    float* out = (float*)d_out;

    const int NB = (N + 1023) >> 10;

    char* ws = (char*)d_ws;
    // Plan A layout
    size_t off_b    = align_up((size_t)N * F_OUT * 4, 256);            // h
    size_t sdst_b   = off_b + align_up(((size_t)N + 1) * 4, 256);      // off
    size_t binned_b = sdst_b + align_up((size_t)E * 4 + 64, 256);      // sdst
    size_t bcnt_b   = binned_b + align_up((size_t)E * 4 + 64, 256);    // binned
    size_t bbase_b  = bcnt_b + 4096;
    size_t gcur_b   = bbase_b + 4096;
    size_t needA    = gcur_b + 4096;
    // Plan B layout (reuses prefix: h, off, sdst; then cursor/cnt/bsum)
    size_t cursor_b = binned_b;
    size_t cnt_b    = cursor_b + align_up((size_t)N * 4, 256);
    size_t bsum_b   = cnt_b + align_up((size_t)N * 4, 256);
    size_t needB    = bsum_b + align_up(4096, 256);

    float* h = (float*)ws;
    const int nbt = (E + BIN_TILE - 1) / BIN_TILE;

    if (ws_size >= needA && N <= (1 << 17) && NB <= 1024) {
        unsigned* off    = (unsigned*)(ws + off_b);
        int*      sdst   = (int*)(ws + sdst_b);
        unsigned* binned = (unsigned*)(ws + binned_b);
        unsigned* bcnt   = (unsigned*)(ws + bcnt_b);
        unsigned* bbase  = (unsigned*)(ws + bbase_b);
        unsigned* gcur   = (unsigned*)(ws + gcur_b);

        hipMemsetAsync(bcnt, 0, (size_t)NB * 4, stream);
        gemm_xw<<<(N + 127) / 128, 256, 0, stream>>>(x, W, h, N);
        bucket_count<<<nbt, 256, 0, stream>>>(ei, bcnt, E, NB);
        scan_buckets<<<1, 256, 0, stream>>>(bcnt, bbase, gcur, NB);
        binA<<<nbt, 256, 0, stream>>>(ei, gcur, binned, E, NB);
        binB<<<NB, 256, 0, stream>>>(binned, bbase, bcnt, off, sdst, N, E, NB);
        node_kernel<<<((size_t)N * 64 + 255) / 256, 256, 0, stream>>>(off, sdst, h, a, out, N);
    } else if (ws_size >= needB) {
        unsigned* off    = (unsigned*)(ws + off_b);
        int*      sdst   = (int*)(ws + sdst_b);
        unsigned* cursor = (unsigned*)(ws + cursor_b);
        unsigned* cnt    = (unsigned*)(ws + cnt_b);
        unsigned* bsum   = (unsigned*)(ws + bsum_b);
        const int nb2 = (N + 2047) / 2048;

        hipMemsetAsync(cnt, 0, (size_t)N * 4, stream);
        gemm_xw<<<(N + 127) / 128, 256, 0, stream>>>(x, W, h, N);
        hist_kernel<<<(E + 255) / 256, 256, 0, stream>>>(ei, cnt, E);
        scan1<<<nb2, 256, 0, stream>>>(cnt, bsum, N);
        scan2<<<1, 128, 0, stream>>>(bsum, off, nb2, N);
        scan3<<<nb2, 256, 0, stream>>>(cnt, bsum, off, cursor, N);
        scatter_kernel<<<(E + 255) / 256, 256, 0, stream>>>(ei, cursor, sdst, E);
        node_kernel<<<((size_t)N * 64 + 255) / 256, 256, 0, stream>>>(off, sdst, h, a, out, N);
    } else {
        float* rowsum = (float*)(ws + off_b);
        hipMemsetAsync(d_out, 0, (size_t)N * F_OUT * sizeof(float), stream);
        hipMemsetAsync(rowsum, 0, (size_t)N * sizeof(float), stream);
        gemm_xw<<<(N + 127) / 128, 256, 0, stream>>>(x, W, h, N);
        edge_kernel<<<2048, 256, 0, stream>>>(ei, h, a, out, rowsum, E);
        finalize<<<((size_t)N * F_OUT + 255) / 256, 256, 0, stream>>>(out, rowsum, N * F_OUT);
    }
}

// Round 6
// 183.086 us; speedup vs baseline: 2.9269x; 1.1864x over previous
//
#include <hip/hip_runtime.h>

#define F_IN 128
#define F_OUT 64
#define BIN_TILE 2048
#define BIN_CAP 24576   // LDS staging capacity per bucket (96 KB)

#define LK_A 0.505f     // leaky(v) = LK_A*v + LK_B*|v|  == leaky_relu(v, 0.01)
#define LK_B 0.495f

__device__ __forceinline__ float leaky(float v) {
    return fmaf(LK_B, fabsf(v), LK_A * v);
}

// Full-wave (64-lane) sum via DPP — result uniform across wave.
__device__ __forceinline__ float wave_sum(float v) {
    v += __builtin_bit_cast(float, __builtin_amdgcn_update_dpp(0, __builtin_bit_cast(int, v), 0x111, 0xf, 0xf, true)); // row_shr:1
    v += __builtin_bit_cast(float, __builtin_amdgcn_update_dpp(0, __builtin_bit_cast(int, v), 0x112, 0xf, 0xf, true)); // row_shr:2
    v += __builtin_bit_cast(float, __builtin_amdgcn_update_dpp(0, __builtin_bit_cast(int, v), 0x114, 0xf, 0xe, true)); // row_shr:4
    v += __builtin_bit_cast(float, __builtin_amdgcn_update_dpp(0, __builtin_bit_cast(int, v), 0x118, 0xf, 0xc, true)); // row_shr:8
    v += __builtin_bit_cast(float, __builtin_amdgcn_update_dpp(0, __builtin_bit_cast(int, v), 0x142, 0xa, 0xf, true)); // row_bcast:15
    v += __builtin_bit_cast(float, __builtin_amdgcn_update_dpp(0, __builtin_bit_cast(int, v), 0x143, 0xc, 0xf, true)); // row_bcast:31
    return __builtin_bit_cast(float, __builtin_amdgcn_readlane(__builtin_bit_cast(int, v), 63));
}

// 16-lane butterfly sum, all via DPP (VALU pipe): xor1, xor2, 8-mirror, 16-mirror.
// Every lane ends with the sum of its 16-lane row group.
__device__ __forceinline__ float sum16(float v) {
    v += __builtin_bit_cast(float, __builtin_amdgcn_update_dpp(0, __builtin_bit_cast(int, v), 0xB1, 0xf, 0xf, true));  // quad_perm [1,0,3,2]
    v += __builtin_bit_cast(float, __builtin_amdgcn_update_dpp(0, __builtin_bit_cast(int, v), 0x4E, 0xf, 0xf, true));  // quad_perm [2,3,0,1]
    v += __builtin_bit_cast(float, __builtin_amdgcn_update_dpp(0, __builtin_bit_cast(int, v), 0x141, 0xf, 0xf, true)); // row_half_mirror
    v += __builtin_bit_cast(float, __builtin_amdgcn_update_dpp(0, __builtin_bit_cast(int, v), 0x140, 0xf, 0xf, true)); // row_mirror
    return v;
}

// ---------------- Kernel 1: h = x @ W (128 rows x 64 cols per block) ----------------
__global__ __launch_bounds__(256) void gemm_xw(const float* __restrict__ x,
                                               const float* __restrict__ W,
                                               float* __restrict__ h, int N) {
    __shared__ float w_lds[F_IN][F_OUT];   // 32 KB
    {
        const float4* Wv = (const float4*)W;
        float4* wl = (float4*)w_lds;
        for (int i = threadIdx.x; i < F_IN * F_OUT / 4; i += 256) wl[i] = Wv[i];
    }
    __syncthreads();

    const int cg = threadIdx.x & 15;
    const int rs = threadIdx.x >> 4;
    const int row0 = blockIdx.x * 128 + rs * 8;

    float4 acc[8];
#pragma unroll
    for (int i = 0; i < 8; ++i) acc[i] = make_float4(0.f, 0.f, 0.f, 0.f);

    for (int k4 = 0; k4 < F_IN / 4; ++k4) {
        float4 wv[4];
#pragma unroll
        for (int kk = 0; kk < 4; ++kk)
            wv[kk] = *(const float4*)&w_lds[k4 * 4 + kk][cg * 4];

        float4 xv[8];
#pragma unroll
        for (int i = 0; i < 8; ++i) {
            int r = row0 + i; if (r >= N) r = N - 1;
            xv[i] = *(const float4*)(x + (size_t)r * F_IN + k4 * 4);
        }
#pragma unroll
        for (int i = 0; i < 8; ++i) {
            acc[i].x = fmaf(xv[i].x, wv[0].x, acc[i].x);
            acc[i].y = fmaf(xv[i].x, wv[0].y, acc[i].y);
            acc[i].z = fmaf(xv[i].x, wv[0].z, acc[i].z);
            acc[i].w = fmaf(xv[i].x, wv[0].w, acc[i].w);
            acc[i].x = fmaf(xv[i].y, wv[1].x, acc[i].x);
            acc[i].y = fmaf(xv[i].y, wv[1].y, acc[i].y);
            acc[i].z = fmaf(xv[i].y, wv[1].z, acc[i].z);
            acc[i].w = fmaf(xv[i].y, wv[1].w, acc[i].w);
            acc[i].x = fmaf(xv[i].z, wv[2].x, acc[i].x);
            acc[i].y = fmaf(xv[i].z, wv[2].y, acc[i].y);
            acc[i].z = fmaf(xv[i].z, wv[2].z, acc[i].z);
            acc[i].w = fmaf(xv[i].z, wv[2].w, acc[i].w);
            acc[i].x = fmaf(xv[i].w, wv[3].x, acc[i].x);
            acc[i].y = fmaf(xv[i].w, wv[3].y, acc[i].y);
            acc[i].z = fmaf(xv[i].w, wv[3].z, acc[i].z);
            acc[i].w = fmaf(xv[i].w, wv[3].w, acc[i].w);
        }
    }
#pragma unroll
    for (int i = 0; i < 8; ++i) {
        const int r = row0 + i;
        if (r < N) *(float4*)(h + (size_t)r * F_OUT + cg * 4) = acc[i];
    }
}

// ---------------- 2-level binned CSR build (unchanged from round 5) ----------------
__global__ __launch_bounds__(256) void bucket_count(const int* __restrict__ ei,
                                                    unsigned* __restrict__ bcnt, int E, int NB) {
    __shared__ unsigned hc[1024];
    const int t = threadIdx.x;
    for (int i = t; i < NB; i += 256) hc[i] = 0;
    __syncthreads();
    const int base = blockIdx.x * BIN_TILE;
#pragma unroll
    for (int i = 0; i < 8; ++i) {
        const int e = base + i * 256 + t;
        if (e < E) atomicAdd(&hc[((unsigned)ei[e]) >> 10], 1u);
    }
    __syncthreads();
    for (int i = t; i < NB; i += 256)
        if (hc[i]) atomicAdd(&bcnt[i], hc[i]);
}

__global__ __launch_bounds__(256) void scan_buckets(const unsigned* __restrict__ bcnt,
                                                    unsigned* __restrict__ bbase,
                                                    unsigned* __restrict__ gcur, int NB) {
    __shared__ unsigned v[1024];
    __shared__ unsigned ts[256];
    const int t = threadIdx.x;
    for (int i = t; i < 1024; i += 256) v[i] = (i < NB) ? bcnt[i] : 0u;
    __syncthreads();
    unsigned s = 0;
#pragma unroll
    for (int j = 0; j < 4; ++j) s += v[t * 4 + j];
    ts[t] = s;
    __syncthreads();
    for (int st = 1; st < 256; st <<= 1) {
        const unsigned add = (t >= st) ? ts[t - st] : 0u;
        __syncthreads();
        ts[t] += add;
        __syncthreads();
    }
    unsigned run = (t > 0) ? ts[t - 1] : 0u;
#pragma unroll
    for (int j = 0; j < 4; ++j) {
        const int i = t * 4 + j;
        const unsigned c = v[i];
        if (i < NB) { bbase[i] = run; gcur[i] = run; }
        run += c;
    }
}

__global__ __launch_bounds__(256) void binA(const int* __restrict__ ei,
                                            unsigned* __restrict__ gcur,
                                            unsigned* __restrict__ binned, int E, int NB) {
    __shared__ unsigned lcnt[1024];
    __shared__ unsigned lbase[1024];
    const int t = threadIdx.x;
    for (int i = t; i < NB; i += 256) lcnt[i] = 0;
    __syncthreads();
    const int base = blockIdx.x * BIN_TILE;
    unsigned pk[8], bk[8], rk[8];
#pragma unroll
    for (int i = 0; i < 8; ++i) {
        const int e = base + i * 256 + t;
        if (e < E) {
            const unsigned s = (unsigned)ei[e];
            const unsigned d = (unsigned)ei[E + e];
            bk[i] = s >> 10;
            pk[i] = ((s & 1023u) << 17) | d;
            rk[i] = atomicAdd(&lcnt[bk[i]], 1u);
        }
    }
    __syncthreads();
    for (int i = t; i < NB; i += 256) {
        const unsigned c = lcnt[i];
        lbase[i] = c ? atomicAdd(&gcur[i], c) : 0u;
    }
    __syncthreads();
#pragma unroll
    for (int i = 0; i < 8; ++i) {
        const int e = base + i * 256 + t;
        if (e < E) binned[lbase[bk[i]] + rk[i]] = pk[i];
    }
}

__global__ __launch_bounds__(256) void binB(const unsigned* __restrict__ binned,
                                            const unsigned* __restrict__ bbase,
                                            const unsigned* __restrict__ bcnt,
                                            unsigned* __restrict__ off,
                                            int* __restrict__ sdst, int N, int E, int NB) {
    __shared__ unsigned stg[BIN_CAP];    // 96 KB
    __shared__ unsigned ncnt[1024];
    __shared__ unsigned ts[256];
    const int b = blockIdx.x;
    const int t = threadIdx.x;
    const unsigned beg = bbase[b];
    const unsigned sz = bcnt[b];
    const unsigned ncap = (sz < (unsigned)BIN_CAP) ? sz : (unsigned)BIN_CAP;

    for (int i = t; i < 1024; i += 256) ncnt[i] = 0;
    for (unsigned i = t; i < ncap; i += 256) stg[i] = binned[beg + i];
    __syncthreads();

    for (unsigned i = t; i < sz; i += 256) {
        const unsigned p = (i < ncap) ? stg[i] : binned[beg + i];
        atomicAdd(&ncnt[p >> 17], 1u);
    }
    __syncthreads();

    unsigned loc[4]; unsigned s = 0;
#pragma unroll
    for (int j = 0; j < 4; ++j) { loc[j] = ncnt[t * 4 + j]; s += loc[j]; }
    ts[t] = s;
    __syncthreads();
    for (int st = 1; st < 256; st <<= 1) {
        const unsigned add = (t >= st) ? ts[t - st] : 0u;
        __syncthreads();
        ts[t] += add;
        __syncthreads();
    }
    unsigned run = (t > 0) ? ts[t - 1] : 0u;
#pragma unroll
    for (int j = 0; j < 4; ++j) { const unsigned c = loc[j]; ncnt[t * 4 + j] = run; run += c; }
    __syncthreads();

    const int node0 = b << 10;
    for (int j = t; j < 1024; j += 256) {
        const int g = node0 + j;
        if (g < N) off[g] = beg + ncnt[j];
    }
    if (b == NB - 1 && t == 0) off[N] = (unsigned)E;
    __syncthreads();

    for (unsigned i = t; i < sz; i += 256) {
        const unsigned p = (i < ncap) ? stg[i] : binned[beg + i];
        const unsigned pos = atomicAdd(&ncnt[p >> 17], 1u);
        sdst[beg + pos] = (int)(p & 0x1FFFFu);
    }
}

// ---------------- Fused per-node kernel: 4 edges/wave, 16 lanes x float4 per edge ----------------
// score(s,d) = cs(s) + [ hd.b1 + 0.495(|hs+hd|.a2 + |hs-hd|.a3) ]
// cs(s) = hs.(a0 + 0.505(a2+a3)),  b1 = a1 + 0.505(a2-a3)
__global__ __launch_bounds__(256) void node_kernel(const unsigned* __restrict__ off,
                                                   const int* __restrict__ sdst,
                                                   const float* __restrict__ h,
                                                   const float* __restrict__ a,
                                                   float* __restrict__ out, int N) {
    const int lane = threadIdx.x & 63;
    const int slot = lane >> 4;          // edge slot 0..3
    const int q    = lane & 15;          // feature quad 0..15
    int node = (int)((blockIdx.x * 256u + threadIdx.x) >> 6);
    if (node >= N) return;
    node = __builtin_amdgcn_readfirstlane(node);

    const float4 A0 = *(const float4*)(a + q * 4);
    const float4 A1 = *(const float4*)(a + 64 + q * 4);
    const float4 A2 = *(const float4*)(a + 128 + q * 4);
    const float4 A3 = *(const float4*)(a + 192 + q * 4);

    float4 b1, a2b, a3b, a0m;
    b1.x = fmaf(LK_A, A2.x - A3.x, A1.x); b1.y = fmaf(LK_A, A2.y - A3.y, A1.y);
    b1.z = fmaf(LK_A, A2.z - A3.z, A1.z); b1.w = fmaf(LK_A, A2.w - A3.w, A1.w);
    a2b.x = LK_B * A2.x; a2b.y = LK_B * A2.y; a2b.z = LK_B * A2.z; a2b.w = LK_B * A2.w;
    a3b.x = LK_B * A3.x; a3b.y = LK_B * A3.y; a3b.z = LK_B * A3.z; a3b.w = LK_B * A3.w;
    a0m.x = fmaf(LK_A, A2.x + A3.x, A0.x); a0m.y = fmaf(LK_A, A2.y + A3.y, A0.y);
    a0m.z = fmaf(LK_A, A2.z + A3.z, A0.z); a0m.w = fmaf(LK_A, A2.w + A3.w, A0.w);

    const int beg = (int)__builtin_amdgcn_readfirstlane((int)off[node]);
    const int end = (int)__builtin_amdgcn_readfirstlane((int)off[node + 1]);

    const float4 hs = *(const float4*)(h + (size_t)node * F_OUT + q * 4);

    // per-node constant score part (uniform within each 16-lane row)
    float csp = hs.x * a0m.x + hs.y * a0m.y + hs.z * a0m.z + hs.w * a0m.w;
    const float cs = sum16(csp);

    float4 acc = make_float4(0.f, 0.f, 0.f, 0.f);
    float rsum = 0.f;

    if (beg < end) {
        const int endm1 = end - 1;
        int eA = beg + slot; if (eA > endm1) eA = endm1;
        int dA = sdst[eA];
        float4 gA = *(const float4*)(h + ((size_t)dA << 6) + q * 4);
        int dB = dA;
        if (beg + 4 < end) {
            int eB = beg + 4 + slot; if (eB > endm1) eB = endm1;
            dB = sdst[eB];
        }

        for (int base = beg; base < end; base += 4) {
            float4 gB = gA;
            int dC = dB;
            if (base + 4 < end)
                gB = *(const float4*)(h + ((size_t)dB << 6) + q * 4);
            if (base + 8 < end) {
                int eC = base + 8 + slot; if (eC > endm1) eC = endm1;
                dC = sdst[eC];
            }

            // per-edge reduced part
            const float s1x = hs.x + gA.x, s1y = hs.y + gA.y, s1z = hs.z + gA.z, s1w = hs.w + gA.w;
            const float s2x = hs.x - gA.x, s2y = hs.y - gA.y, s2z = hs.z - gA.z, s2w = hs.w - gA.w;
            float px = gA.x * b1.x, py = gA.y * b1.y, pz = gA.z * b1.z, pw = gA.w * b1.w;
            px = fmaf(fabsf(s1x), a2b.x, px); py = fmaf(fabsf(s1y), a2b.y, py);
            pz = fmaf(fabsf(s1z), a2b.z, pz); pw = fmaf(fabsf(s1w), a2b.w, pw);
            px = fmaf(fabsf(s2x), a3b.x, px); py = fmaf(fabsf(s2y), a3b.y, py);
            pz = fmaf(fabsf(s2z), a3b.z, pz); pw = fmaf(fabsf(s2w), a3b.w, pw);
            const float R = sum16((px + py) + (pz + pw));   // all 16 lanes get their edge's sum

            float e = __expf(-leaky(cs + R));
            e = (base + slot < end) ? e : 0.f;

            acc.x = fmaf(e, gA.x, acc.x);
            acc.y = fmaf(e, gA.y, acc.y);
            acc.z = fmaf(e, gA.z, acc.z);
            acc.w = fmaf(e, gA.w, acc.w);
            rsum += e;

            gA = gB; dB = dC;
        }
    }

    // cross-slot (4 edge slots) reduction: xor 16 and 32
    acc.x += __shfl_xor(acc.x, 16); acc.x += __shfl_xor(acc.x, 32);
    acc.y += __shfl_xor(acc.y, 16); acc.y += __shfl_xor(acc.y, 32);
    acc.z += __shfl_xor(acc.z, 16); acc.z += __shfl_xor(acc.z, 32);
    acc.w += __shfl_xor(acc.w, 16); acc.w += __shfl_xor(acc.w, 32);
    rsum  += __shfl_xor(rsum, 16);  rsum  += __shfl_xor(rsum, 32);

    if (slot == 0) {
        const float inv = 1.f / (rsum + 1e-16f);
        float4 o; o.x = acc.x * inv; o.y = acc.y * inv; o.z = acc.z * inv; o.w = acc.w * inv;
        *(float4*)(out + (size_t)node * F_OUT + q * 4) = o;
    }
}

// ---------------- Plan B: old CSR build ----------------
__global__ __launch_bounds__(256) void hist_kernel(const int* __restrict__ ei,
                                                   unsigned* __restrict__ cnt, int E) {
    const int e = blockIdx.x * 256 + threadIdx.x;
    if (e < E) atomicAdd(&cnt[ei[e]], 1u);
}

__global__ __launch_bounds__(256) void scan1(const unsigned* __restrict__ cnt,
                                             unsigned* __restrict__ bsum, int n) {
    __shared__ unsigned lds[256];
    const int t = threadIdx.x;
    const int base = blockIdx.x * 2048 + t * 8;
    unsigned s = 0;
#pragma unroll
    for (int i = 0; i < 8; ++i) { const int idx = base + i; if (idx < n) s += cnt[idx]; }
    lds[t] = s; __syncthreads();
    for (int st = 128; st > 0; st >>= 1) {
        if (t < st) lds[t] += lds[t + st];
        __syncthreads();
    }
    if (t == 0) bsum[blockIdx.x] = lds[0];
}

__global__ __launch_bounds__(128) void scan2(unsigned* __restrict__ bsum,
                                             unsigned* __restrict__ off, int nb, int n) {
    __shared__ unsigned lds[128];
    const int t = threadIdx.x;
    if (t < nb) lds[t] = bsum[t];
    __syncthreads();
    if (t == 0) {
        unsigned run = 0;
        for (int i = 0; i < nb; ++i) { const unsigned v = lds[i]; lds[i] = run; run += v; }
        off[n] = run;
    }
    __syncthreads();
    if (t < nb) bsum[t] = lds[t];
}

__global__ __launch_bounds__(256) void scan3(const unsigned* __restrict__ cnt,
                                             const unsigned* __restrict__ bsum,
                                             unsigned* __restrict__ off,
                                             unsigned* __restrict__ cursor, int n) {
    __shared__ unsigned lds[256];
    const int t = threadIdx.x;
    const int base = blockIdx.x * 2048 + t * 8;
    unsigned v[8]; unsigned s = 0;
#pragma unroll
    for (int i = 0; i < 8; ++i) { const int idx = base + i; v[i] = (idx < n) ? cnt[idx] : 0u; s += v[i]; }
    lds[t] = s; __syncthreads();
    for (int st = 1; st < 256; st <<= 1) {
        const unsigned add = (t >= st) ? lds[t - st] : 0u;
        __syncthreads();
        lds[t] += add;
        __syncthreads();
    }
    unsigned excl = (t > 0 ? lds[t - 1] : 0u) + bsum[blockIdx.x];
#pragma unroll
    for (int i = 0; i < 8; ++i) {
        const int idx = base + i;
        if (idx < n) { off[idx] = excl; cursor[idx] = excl; excl += v[i]; }
    }
}

__global__ __launch_bounds__(256) void scatter_kernel(const int* __restrict__ ei,
                                                      unsigned* __restrict__ cursor,
                                                      int* __restrict__ sdst, int E) {
    const int e = blockIdx.x * 256 + threadIdx.x;
    if (e >= E) return;
    const int s = ei[e];
    const int d = ei[E + e];
    const unsigned pos = atomicAdd(&cursor[s], 1u);
    sdst[pos] = d;
}

// ---------------- Plan C: atomic fallback ----------------
__device__ __forceinline__ float edge_part(float hs, float hd, float a1, float a2, float a3) {
    float p = hd * a1;
    p = fmaf(leaky(hs + hd), a2, p);
    p = fmaf(leaky(hs - hd), a3, p);
    return p;
}

__global__ __launch_bounds__(256) void edge_kernel(const int* __restrict__ ei,
                                                   const float* __restrict__ h,
                                                   const float* __restrict__ a,
                                                   float* __restrict__ hprime,
                                                   float* __restrict__ rowsum,
                                                   int E) {
    const int lane = threadIdx.x & 63;
    const int wave = (int)((blockIdx.x * blockDim.x + threadIdx.x) >> 6);
    const int nwaves = (int)((gridDim.x * blockDim.x) >> 6);
    const float a0 = a[lane], a1 = a[64 + lane], a2 = a[128 + lane], a3 = a[192 + lane];
    for (int e = wave; e < E; e += nwaves) {
        const int s = ei[e];
        const int d = ei[E + e];
        const float hs = h[(size_t)s * F_OUT + lane];
        const float hd = h[(size_t)d * F_OUT + lane];
        const float part = wave_sum(hs * a0 + edge_part(hs, hd, a1, a2, a3));
        const float ee = __expf(-leaky(part));
        atomicAdd(&hprime[(size_t)s * F_OUT + lane], ee * hd);
        if (lane == 0) atomicAdd(&rowsum[s], ee);
    }
}

__global__ __launch_bounds__(256) void finalize(float* __restrict__ out,
                                                const float* __restrict__ rowsum,
                                                int total) {
    const int i = blockIdx.x * blockDim.x + threadIdx.x;
    if (i < total) out[i] = out[i] / (rowsum[i >> 6] + 1e-16f);
}

static inline size_t align_up(size_t v, size_t a) { return (v + a - 1) & ~(a - 1); }

extern "C" void kernel_launch(void* const* d_in, const int* in_sizes, int n_in,
                              void* d_out, int out_size, void* d_ws, size_t ws_size,
                              hipStream_t stream) {
    const float* x  = (const float*)d_in[0];
    const int*   ei = (const int*)d_in[1];
    const float* W  = (const float*)d_in[2];
    const float* a  = (const float*)d_in[3];

    const int N = in_sizes[0] / F_IN;
    const int E = in_sizes[1] / 2;
    float* out = (float*)d_out;

    const int NB = (N + 1023) >> 10;

    char* ws = (char*)d_ws;
    size_t off_b    = align_up((size_t)N * F_OUT * 4, 256);            // h
    size_t sdst_b   = off_b + align_up(((size_t)N + 1) * 4, 256);      // off
    size_t binned_b = sdst_b + align_up((size_t)E * 4 + 64, 256);      // sdst
    size_t bcnt_b   = binned_b + align_up((size_t)E * 4 + 64, 256);    // binned
    size_t bbase_b  = bcnt_b + 4096;
    size_t gcur_b   = bbase_b + 4096;
    size_t needA    = gcur_b + 4096;
    size_t cursor_b = binned_b;
    size_t cnt_b    = cursor_b + align_up((size_t)N * 4, 256);
    size_t bsum_b   = cnt_b + align_up((size_t)N * 4, 256);
    size_t needB    = bsum_b + align_up(4096, 256);

    float* h = (float*)ws;
    const int nbt = (E + BIN_TILE - 1) / BIN_TILE;

    if (ws_size >= needA && N <= (1 << 17) && NB <= 1024) {
        unsigned* off    = (unsigned*)(ws + off_b);
        int*      sdst   = (int*)(ws + sdst_b);
        unsigned* binned = (unsigned*)(ws + binned_b);
        unsigned* bcnt   = (unsigned*)(ws + bcnt_b);
        unsigned* bbase  = (unsigned*)(ws + bbase_b);
        unsigned* gcur   = (unsigned*)(ws + gcur_b);

        hipMemsetAsync(bcnt, 0, (size_t)NB * 4, stream);
        gemm_xw<<<(N + 127) / 128, 256, 0, stream>>>(x, W, h, N);
        bucket_count<<<nbt, 256, 0, stream>>>(ei, bcnt, E, NB);
        scan_buckets<<<1, 256, 0, stream>>>(bcnt, bbase, gcur, NB);
        binA<<<nbt, 256, 0, stream>>>(ei, gcur, binned, E, NB);
        binB<<<NB, 256, 0, stream>>>(binned, bbase, bcnt, off, sdst, N, E, NB);
        node_kernel<<<((size_t)N * 64 + 255) / 256, 256, 0, stream>>>(off, sdst, h, a, out, N);
    } else if (ws_size >= needB) {
        unsigned* off    = (unsigned*)(ws + off_b);
        int*      sdst   = (int*)(ws + sdst_b);
        unsigned* cursor = (unsigned*)(ws + cursor_b);
        unsigned* cnt    = (unsigned*)(ws + cnt_b);
        unsigned* bsum   = (unsigned*)(ws + bsum_b);
        const int nb2 = (N + 2047) / 2048;

        hipMemsetAsync(cnt, 0, (size_t)N * 4, stream);
        gemm_xw<<<(N + 127) / 128, 256, 0, stream>>>(x, W, h, N);
        hist_kernel<<<(E + 255) / 256, 256, 0, stream>>>(ei, cnt, E);
        scan1<<<nb2, 256, 0, stream>>>(cnt, bsum, N);
        scan2<<<1, 128, 0, stream>>>(bsum, off, nb2, N);
        scan3<<<nb2, 256, 0, stream>>>(cnt, bsum, off, cursor, N);
        scatter_kernel<<<(E + 255) / 256, 256, 0, stream>>>(ei, cursor, sdst, E);
        node_kernel<<<((size_t)N * 64 + 255) / 256, 256, 0, stream>>>(off, sdst, h, a, out, N);
    } else {
        float* rowsum = (float*)(ws + off_b);
        hipMemsetAsync(d_out, 0, (size_t)N * F_OUT * sizeof(float), stream);
        hipMemsetAsync(rowsum, 0, (size_t)N * sizeof(float), stream);
        gemm_xw<<<(N + 127) / 128, 256, 0, stream>>>(x, W, h, N);
        edge_kernel<<<2048, 256, 0, stream>>>(ei, h, a, out, rowsum, E);
        finalize<<<((size_t)N * F_OUT + 255) / 256, 256, 0, stream>>>(out, rowsum, N * F_OUT);
    }
}

// Round 7
// 175.422 us; speedup vs baseline: 3.0548x; 1.0437x over previous
//
#include <hip/hip_runtime.h>
#include <hip/hip_fp16.h>

#define F_IN 128
#define F_OUT 64
#define BIN_TILE 2048
#define BSHIFT 8            // 256 nodes per bucket
#define BNODES 256
#define BIN_CAP 6144        // LDS staging per bucket (24 KB); overflow reads global

#define LK_A 0.505f         // leaky(v) = LK_A*v + LK_B*|v|  == leaky_relu(v, 0.01)
#define LK_B 0.495f

__device__ __forceinline__ float leaky(float v) {
    return fmaf(LK_B, fabsf(v), LK_A * v);
}

// Full-wave (64-lane) sum via DPP — result uniform across wave.
__device__ __forceinline__ float wave_sum(float v) {
    v += __builtin_bit_cast(float, __builtin_amdgcn_update_dpp(0, __builtin_bit_cast(int, v), 0x111, 0xf, 0xf, true)); // row_shr:1
    v += __builtin_bit_cast(float, __builtin_amdgcn_update_dpp(0, __builtin_bit_cast(int, v), 0x112, 0xf, 0xf, true)); // row_shr:2
    v += __builtin_bit_cast(float, __builtin_amdgcn_update_dpp(0, __builtin_bit_cast(int, v), 0x114, 0xf, 0xe, true)); // row_shr:4
    v += __builtin_bit_cast(float, __builtin_amdgcn_update_dpp(0, __builtin_bit_cast(int, v), 0x118, 0xf, 0xc, true)); // row_shr:8
    v += __builtin_bit_cast(float, __builtin_amdgcn_update_dpp(0, __builtin_bit_cast(int, v), 0x142, 0xa, 0xf, true)); // row_bcast:15
    v += __builtin_bit_cast(float, __builtin_amdgcn_update_dpp(0, __builtin_bit_cast(int, v), 0x143, 0xc, 0xf, true)); // row_bcast:31
    return __builtin_bit_cast(float, __builtin_amdgcn_readlane(__builtin_bit_cast(int, v), 63));
}

// 16-lane butterfly sum via DPP; every lane gets its 16-lane group's sum.
__device__ __forceinline__ float sum16(float v) {
    v += __builtin_bit_cast(float, __builtin_amdgcn_update_dpp(0, __builtin_bit_cast(int, v), 0xB1, 0xf, 0xf, true));  // quad_perm [1,0,3,2]
    v += __builtin_bit_cast(float, __builtin_amdgcn_update_dpp(0, __builtin_bit_cast(int, v), 0x4E, 0xf, 0xf, true));  // quad_perm [2,3,0,1]
    v += __builtin_bit_cast(float, __builtin_amdgcn_update_dpp(0, __builtin_bit_cast(int, v), 0x141, 0xf, 0xf, true)); // row_half_mirror
    v += __builtin_bit_cast(float, __builtin_amdgcn_update_dpp(0, __builtin_bit_cast(int, v), 0x140, 0xf, 0xf, true)); // row_mirror
    return v;
}

__device__ __forceinline__ float4 cvt4(uint2 u) {
    const float2 f0 = __half22float2(__builtin_bit_cast(__half2, u.x));
    const float2 f1 = __half22float2(__builtin_bit_cast(__half2, u.y));
    return make_float4(f0.x, f0.y, f1.x, f1.y);
}

// ---------------- Kernel 1: h = x @ W, + fused bucket histogram ----------------
// mode bit0: write h16; bit1: write h32; bit2: bucket-histogram of ei[0..E)
__global__ __launch_bounds__(256) void gemm_xw(const float* __restrict__ x,
                                               const float* __restrict__ W,
                                               float* __restrict__ h32,
                                               uint2* __restrict__ h16,
                                               const int* __restrict__ ei,
                                               unsigned* __restrict__ bcnt,
                                               int N, int E, int EPB, int NB, int mode) {
    __shared__ float w_lds[F_IN][F_OUT];   // 32 KB
    __shared__ unsigned hc[1024];          // 4 KB bucket histogram
    {
        const float4* Wv = (const float4*)W;
        float4* wl = (float4*)w_lds;
        for (int i = threadIdx.x; i < F_IN * F_OUT / 4; i += 256) wl[i] = Wv[i];
        if (mode & 4)
            for (int i = threadIdx.x; i < NB; i += 256) hc[i] = 0;
    }
    __syncthreads();

    const int cg = threadIdx.x & 15;
    const int rs = threadIdx.x >> 4;
    const int row0 = blockIdx.x * 128 + rs * 8;

    float4 acc[8];
#pragma unroll
    for (int i = 0; i < 8; ++i) acc[i] = make_float4(0.f, 0.f, 0.f, 0.f);

    for (int k4 = 0; k4 < F_IN / 4; ++k4) {
        float4 wv[4];
#pragma unroll
        for (int kk = 0; kk < 4; ++kk)
            wv[kk] = *(const float4*)&w_lds[k4 * 4 + kk][cg * 4];

        float4 xv[8];
#pragma unroll
        for (int i = 0; i < 8; ++i) {
            int r = row0 + i; if (r >= N) r = N - 1;
            xv[i] = *(const float4*)(x + (size_t)r * F_IN + k4 * 4);
        }
#pragma unroll
        for (int i = 0; i < 8; ++i) {
            acc[i].x = fmaf(xv[i].x, wv[0].x, acc[i].x);
            acc[i].y = fmaf(xv[i].x, wv[0].y, acc[i].y);
            acc[i].z = fmaf(xv[i].x, wv[0].z, acc[i].z);
            acc[i].w = fmaf(xv[i].x, wv[0].w, acc[i].w);
            acc[i].x = fmaf(xv[i].y, wv[1].x, acc[i].x);
            acc[i].y = fmaf(xv[i].y, wv[1].y, acc[i].y);
            acc[i].z = fmaf(xv[i].y, wv[1].z, acc[i].z);
            acc[i].w = fmaf(xv[i].y, wv[1].w, acc[i].w);
            acc[i].x = fmaf(xv[i].z, wv[2].x, acc[i].x);
            acc[i].y = fmaf(xv[i].z, wv[2].y, acc[i].y);
            acc[i].z = fmaf(xv[i].z, wv[2].z, acc[i].z);
            acc[i].w = fmaf(xv[i].z, wv[2].w, acc[i].w);
            acc[i].x = fmaf(xv[i].w, wv[3].x, acc[i].x);
            acc[i].y = fmaf(xv[i].w, wv[3].y, acc[i].y);
            acc[i].z = fmaf(xv[i].w, wv[3].z, acc[i].z);
            acc[i].w = fmaf(xv[i].w, wv[3].w, acc[i].w);
        }
    }
#pragma unroll
    for (int i = 0; i < 8; ++i) {
        const int r = row0 + i;
        if (r < N) {
            if (mode & 2) *(float4*)(h32 + (size_t)r * F_OUT + cg * 4) = acc[i];
            if (mode & 1) {
                uint2 u;
                u.x = __builtin_bit_cast(unsigned, __floats2half2_rn(acc[i].x, acc[i].y));
                u.y = __builtin_bit_cast(unsigned, __floats2half2_rn(acc[i].z, acc[i].w));
                h16[(size_t)r * 16 + cg] = u;
            }
        }
    }

    if (mode & 4) {
        const int e0 = blockIdx.x * EPB;
        const int e1 = min(E, e0 + EPB);
        for (int e = e0 + (int)threadIdx.x; e < e1; e += 256)
            atomicAdd(&hc[((unsigned)ei[e]) >> BSHIFT], 1u);
        __syncthreads();
        for (int i = threadIdx.x; i < NB; i += 256)
            if (hc[i]) atomicAdd(&bcnt[i], hc[i]);
    }
}

// ---------------- binned CSR build ----------------
__global__ __launch_bounds__(256) void scan_buckets(const unsigned* __restrict__ bcnt,
                                                    unsigned* __restrict__ bbase,
                                                    unsigned* __restrict__ gcur, int NB) {
    __shared__ unsigned v[1024];
    __shared__ unsigned ts[256];
    const int t = threadIdx.x;
    for (int i = t; i < 1024; i += 256) v[i] = (i < NB) ? bcnt[i] : 0u;
    __syncthreads();
    unsigned s = 0;
#pragma unroll
    for (int j = 0; j < 4; ++j) s += v[t * 4 + j];
    ts[t] = s;
    __syncthreads();
    for (int st = 1; st < 256; st <<= 1) {
        const unsigned add = (t >= st) ? ts[t - st] : 0u;
        __syncthreads();
        ts[t] += add;
        __syncthreads();
    }
    unsigned run = (t > 0) ? ts[t - 1] : 0u;
#pragma unroll
    for (int j = 0; j < 4; ++j) {
        const int i = t * 4 + j;
        const unsigned c = v[i];
        if (i < NB) { bbase[i] = run; gcur[i] = run; }
        run += c;
    }
}

__global__ __launch_bounds__(256) void binA(const int* __restrict__ ei,
                                            unsigned* __restrict__ gcur,
                                            unsigned* __restrict__ binned, int E, int NB) {
    __shared__ unsigned lcnt[1024];
    __shared__ unsigned lbase[1024];
    const int t = threadIdx.x;
    for (int i = t; i < NB; i += 256) lcnt[i] = 0;
    __syncthreads();
    const int base = blockIdx.x * BIN_TILE;
    unsigned pk[8], bk[8], rk[8];
#pragma unroll
    for (int i = 0; i < 8; ++i) {
        const int e = base + i * 256 + t;
        if (e < E) {
            const unsigned s = (unsigned)ei[e];
            const unsigned d = (unsigned)ei[E + e];
            bk[i] = s >> BSHIFT;
            pk[i] = ((s & (BNODES - 1u)) << 17) | d;
            rk[i] = atomicAdd(&lcnt[bk[i]], 1u);
        }
    }
    __syncthreads();
    for (int i = t; i < NB; i += 256) {
        const unsigned c = lcnt[i];
        lbase[i] = c ? atomicAdd(&gcur[i], c) : 0u;
    }
    __syncthreads();
#pragma unroll
    for (int i = 0; i < 8; ++i) {
        const int e = base + i * 256 + t;
        if (e < E) binned[lbase[bk[i]] + rk[i]] = pk[i];
    }
}

// One block per 256-node bucket: per-node hist + scan in LDS -> off[]; scatter -> sdst[]
__global__ __launch_bounds__(256) void binB(const unsigned* __restrict__ binned,
                                            const unsigned* __restrict__ bbase,
                                            const unsigned* __restrict__ bcnt,
                                            unsigned* __restrict__ off,
                                            int* __restrict__ sdst, int N, int E, int NB) {
    __shared__ unsigned stg[BIN_CAP];    // 24 KB
    __shared__ unsigned ncnt[BNODES];
    __shared__ unsigned ts[256];
    const int b = blockIdx.x;
    const int t = threadIdx.x;
    const unsigned beg = bbase[b];
    const unsigned sz = bcnt[b];
    const unsigned ncap = (sz < (unsigned)BIN_CAP) ? sz : (unsigned)BIN_CAP;

    ncnt[t] = 0;
    for (unsigned i = t; i < ncap; i += 256) stg[i] = binned[beg + i];
    __syncthreads();

    for (unsigned i = t; i < sz; i += 256) {
        const unsigned p = (i < ncap) ? stg[i] : binned[beg + i];
        atomicAdd(&ncnt[p >> 17], 1u);
    }
    __syncthreads();

    const unsigned myc = ncnt[t];
    ts[t] = myc;
    __syncthreads();
    for (int st = 1; st < 256; st <<= 1) {
        const unsigned add = (t >= st) ? ts[t - st] : 0u;
        __syncthreads();
        ts[t] += add;
        __syncthreads();
    }
    const unsigned excl = ts[t] - myc;
    ncnt[t] = excl;                       // becomes cursor
    const int g = (b << BSHIFT) + t;
    if (g < N) off[g] = beg + excl;
    if (b == NB - 1 && t == 0) off[N] = (unsigned)E;
    __syncthreads();

    for (unsigned i = t; i < sz; i += 256) {
        const unsigned p = (i < ncap) ? stg[i] : binned[beg + i];
        const unsigned pos = atomicAdd(&ncnt[p >> 17], 1u);
        sdst[beg + pos] = (int)(p & 0x1FFFFu);
    }
}

// ---------------- Fused per-node kernel: 4 edges/wave, fp16 gathers, depth-2 prefetch ----------------
__global__ __launch_bounds__(256) void node_kernel(const unsigned* __restrict__ off,
                                                   const int* __restrict__ sdst,
                                                   const uint2* __restrict__ h16,
                                                   const float* __restrict__ a,
                                                   float* __restrict__ out, int N) {
    const int lane = threadIdx.x & 63;
    const int slot = lane >> 4;          // edge slot 0..3
    const int q    = lane & 15;          // feature quad 0..15
    int node = (int)((blockIdx.x * 256u + threadIdx.x) >> 6);
    if (node >= N) return;
    node = __builtin_amdgcn_readfirstlane(node);

    const float4 A0 = *(const float4*)(a + q * 4);
    const float4 A1 = *(const float4*)(a + 64 + q * 4);
    const float4 A2 = *(const float4*)(a + 128 + q * 4);
    const float4 A3 = *(const float4*)(a + 192 + q * 4);

    float4 b1, a2b, a3b, a0m;
    b1.x = fmaf(LK_A, A2.x - A3.x, A1.x); b1.y = fmaf(LK_A, A2.y - A3.y, A1.y);
    b1.z = fmaf(LK_A, A2.z - A3.z, A1.z); b1.w = fmaf(LK_A, A2.w - A3.w, A1.w);
    a2b.x = LK_B * A2.x; a2b.y = LK_B * A2.y; a2b.z = LK_B * A2.z; a2b.w = LK_B * A2.w;
    a3b.x = LK_B * A3.x; a3b.y = LK_B * A3.y; a3b.z = LK_B * A3.z; a3b.w = LK_B * A3.w;
    a0m.x = fmaf(LK_A, A2.x + A3.x, A0.x); a0m.y = fmaf(LK_A, A2.y + A3.y, A0.y);
    a0m.z = fmaf(LK_A, A2.z + A3.z, A0.z); a0m.w = fmaf(LK_A, A2.w + A3.w, A0.w);

    const int beg = (int)__builtin_amdgcn_readfirstlane((int)off[node]);
    const int end = (int)__builtin_amdgcn_readfirstlane((int)off[node + 1]);

    const float4 hs = cvt4(h16[(size_t)node * 16 + q]);
    const float cs = sum16(hs.x * a0m.x + hs.y * a0m.y + hs.z * a0m.z + hs.w * a0m.w);

    float4 acc = make_float4(0.f, 0.f, 0.f, 0.f);
    float rsum = 0.f;

    if (beg < end) {
        const int endm1 = end - 1;
        int e0 = beg + slot; if (e0 > endm1) e0 = endm1;
        uint2 uA = h16[((size_t)sdst[e0] << 4) + q];
        int dB = sdst[e0];
        if (beg + 4 < end) {
            int e1 = beg + 4 + slot; if (e1 > endm1) e1 = endm1;
            dB = sdst[e1];
        }
        uint2 uB = h16[((size_t)dB << 4) + q];
        int dC = dB;
        if (beg + 8 < end) {
            int e2 = beg + 8 + slot; if (e2 > endm1) e2 = endm1;
            dC = sdst[e2];
        }

        for (int base = beg; base < end; base += 4) {
            uint2 uC = uB;
            int dD = dC;
            if (base + 8 < end)
                uC = h16[((size_t)dC << 4) + q];         // gather 2 chunks ahead
            if (base + 12 < end) {
                int e3 = base + 12 + slot; if (e3 > endm1) e3 = endm1;
                dD = sdst[e3];
            }

            const float4 gA = cvt4(uA);

            const float s1x = hs.x + gA.x, s1y = hs.y + gA.y, s1z = hs.z + gA.z, s1w = hs.w + gA.w;
            const float s2x = hs.x - gA.x, s2y = hs.y - gA.y, s2z = hs.z - gA.z, s2w = hs.w - gA.w;
            float px = gA.x * b1.x, py = gA.y * b1.y, pz = gA.z * b1.z, pw = gA.w * b1.w;
            px = fmaf(fabsf(s1x), a2b.x, px); py = fmaf(fabsf(s1y), a2b.y, py);
            pz = fmaf(fabsf(s1z), a2b.z, pz); pw = fmaf(fabsf(s1w), a2b.w, pw);
            px = fmaf(fabsf(s2x), a3b.x, px); py = fmaf(fabsf(s2y), a3b.y, py);
            pz = fmaf(fabsf(s2z), a3b.z, pz); pw = fmaf(fabsf(s2w), a3b.w, pw);
            const float R = sum16((px + py) + (pz + pw));

            float e = __expf(-leaky(cs + R));
            e = (base + slot < end) ? e : 0.f;

            acc.x = fmaf(e, gA.x, acc.x);
            acc.y = fmaf(e, gA.y, acc.y);
            acc.z = fmaf(e, gA.z, acc.z);
            acc.w = fmaf(e, gA.w, acc.w);
            rsum += e;

            uA = uB; uB = uC; dC = dD;
        }
    }

    acc.x += __shfl_xor(acc.x, 16); acc.x += __shfl_xor(acc.x, 32);
    acc.y += __shfl_xor(acc.y, 16); acc.y += __shfl_xor(acc.y, 32);
    acc.z += __shfl_xor(acc.z, 16); acc.z += __shfl_xor(acc.z, 32);
    acc.w += __shfl_xor(acc.w, 16); acc.w += __shfl_xor(acc.w, 32);
    rsum  += __shfl_xor(rsum, 16);  rsum  += __shfl_xor(rsum, 32);

    if (slot == 0) {
        const float inv = 1.f / (rsum + 1e-16f);
        float4 o; o.x = acc.x * inv; o.y = acc.y * inv; o.z = acc.z * inv; o.w = acc.w * inv;
        *(float4*)(out + (size_t)node * F_OUT + q * 4) = o;
    }
}

// ---------------- Plan B: old CSR build ----------------
__global__ __launch_bounds__(256) void hist_kernel(const int* __restrict__ ei,
                                                   unsigned* __restrict__ cnt, int E) {
    const int e = blockIdx.x * 256 + threadIdx.x;
    if (e < E) atomicAdd(&cnt[ei[e]], 1u);
}

__global__ __launch_bounds__(256) void scan1(const unsigned* __restrict__ cnt,
                                             unsigned* __restrict__ bsum, int n) {
    __shared__ unsigned lds[256];
    const int t = threadIdx.x;
    const int base = blockIdx.x * 2048 + t * 8;
    unsigned s = 0;
#pragma unroll
    for (int i = 0; i < 8; ++i) { const int idx = base + i; if (idx < n) s += cnt[idx]; }
    lds[t] = s; __syncthreads();
    for (int st = 128; st > 0; st >>= 1) {
        if (t < st) lds[t] += lds[t + st];
        __syncthreads();
    }
    if (t == 0) bsum[blockIdx.x] = lds[0];
}

__global__ __launch_bounds__(128) void scan2(unsigned* __restrict__ bsum,
                                             unsigned* __restrict__ off, int nb, int n) {
    __shared__ unsigned lds[128];
    const int t = threadIdx.x;
    if (t < nb) lds[t] = bsum[t];
    __syncthreads();
    if (t == 0) {
        unsigned run = 0;
        for (int i = 0; i < nb; ++i) { const unsigned v = lds[i]; lds[i] = run; run += v; }
        off[n] = run;
    }
    __syncthreads();
    if (t < nb) bsum[t] = lds[t];
}

__global__ __launch_bounds__(256) void scan3(const unsigned* __restrict__ cnt,
                                             const unsigned* __restrict__ bsum,
                                             unsigned* __restrict__ off,
                                             unsigned* __restrict__ cursor, int n) {
    __shared__ unsigned lds[256];
    const int t = threadIdx.x;
    const int base = blockIdx.x * 2048 + t * 8;
    unsigned v[8]; unsigned s = 0;
#pragma unroll
    for (int i = 0; i < 8; ++i) { const int idx = base + i; v[i] = (idx < n) ? cnt[idx] : 0u; s += v[i]; }
    lds[t] = s; __syncthreads();
    for (int st = 1; st < 256; st <<= 1) {
        const unsigned add = (t >= st) ? lds[t - st] : 0u;
        __syncthreads();
        lds[t] += add;
        __syncthreads();
    }
    unsigned excl = (t > 0 ? lds[t - 1] : 0u) + bsum[blockIdx.x];
#pragma unroll
    for (int i = 0; i < 8; ++i) {
        const int idx = base + i;
        if (idx < n) { off[idx] = excl; cursor[idx] = excl; excl += v[i]; }
    }
}

__global__ __launch_bounds__(256) void scatter_kernel(const int* __restrict__ ei,
                                                      unsigned* __restrict__ cursor,
                                                      int* __restrict__ sdst, int E) {
    const int e = blockIdx.x * 256 + threadIdx.x;
    if (e >= E) return;
    const int s = ei[e];
    const int d = ei[E + e];
    const unsigned pos = atomicAdd(&cursor[s], 1u);
    sdst[pos] = d;
}

// ---------------- Plan C: atomic fallback ----------------
__device__ __forceinline__ float edge_part(float hs, float hd, float a1, float a2, float a3) {
    float p = hd * a1;
    p = fmaf(leaky(hs + hd), a2, p);
    p = fmaf(leaky(hs - hd), a3, p);
    return p;
}

__global__ __launch_bounds__(256) void edge_kernel(const int* __restrict__ ei,
                                                   const float* __restrict__ h,
                                                   const float* __restrict__ a,
                                                   float* __restrict__ hprime,
                                                   float* __restrict__ rowsum,
                                                   int E) {
    const int lane = threadIdx.x & 63;
    const int wave = (int)((blockIdx.x * blockDim.x + threadIdx.x) >> 6);
    const int nwaves = (int)((gridDim.x * blockDim.x) >> 6);
    const float a0 = a[lane], a1 = a[64 + lane], a2 = a[128 + lane], a3 = a[192 + lane];
    for (int e = wave; e < E; e += nwaves) {
        const int s = ei[e];
        const int d = ei[E + e];
        const float hs = h[(size_t)s * F_OUT + lane];
        const float hd = h[(size_t)d * F_OUT + lane];
        const float part = wave_sum(hs * a0 + edge_part(hs, hd, a1, a2, a3));
        const float ee = __expf(-leaky(part));
        atomicAdd(&hprime[(size_t)s * F_OUT + lane], ee * hd);
        if (lane == 0) atomicAdd(&rowsum[s], ee);
    }
}

__global__ __launch_bounds__(256) void finalize(float* __restrict__ out,
                                                const float* __restrict__ rowsum,
                                                int total) {
    const int i = blockIdx.x * blockDim.x + threadIdx.x;
    if (i < total) out[i] = out[i] / (rowsum[i >> 6] + 1e-16f);
}

static inline size_t align_up(size_t v, size_t a) { return (v + a - 1) & ~(a - 1); }

extern "C" void kernel_launch(void* const* d_in, const int* in_sizes, int n_in,
                              void* d_out, int out_size, void* d_ws, size_t ws_size,
                              hipStream_t stream) {
    const float* x  = (const float*)d_in[0];
    const int*   ei = (const int*)d_in[1];
    const float* W  = (const float*)d_in[2];
    const float* a  = (const float*)d_in[3];

    const int N = in_sizes[0] / F_IN;
    const int E = in_sizes[1] / 2;
    float* out = (float*)d_out;

    const int NB = (N + BNODES - 1) >> BSHIFT;
    const int ngemm = (N + 127) / 128;
    const int EPB = (E + ngemm - 1) / ngemm;
    const int nbt = (E + BIN_TILE - 1) / BIN_TILE;

    char* ws = (char*)d_ws;
    const size_t szh16  = align_up((size_t)N * F_OUT * 2, 256);
    const size_t szoff  = align_up(((size_t)N + 1) * 4, 256);
    const size_t szedge = align_up((size_t)E * 4 + 64, 256);

    // common prefix: h16 | off | sdst
    const size_t off_b  = szh16;
    const size_t sdst_b = off_b + szoff;
    // plan A tail: binned | bcnt | bbase | gcur
    const size_t binned_b = sdst_b + szedge;
    const size_t bcnt_b   = binned_b + szedge;
    const size_t bbase_b  = bcnt_b + 4096;
    const size_t gcur_b   = bbase_b + 4096;
    const size_t needA    = gcur_b + 4096;
    // plan B tail: cursor | cnt | bsum
    const size_t cursor_b = sdst_b + szedge;
    const size_t cnt_b    = cursor_b + align_up((size_t)N * 4, 256);
    const size_t bsum_b   = cnt_b + align_up((size_t)N * 4, 256);
    const size_t needB    = bsum_b + 4096;
    // plan C: h32 | rowsum
    const size_t needC    = align_up((size_t)N * F_OUT * 4, 256) + (size_t)N * 4;

    uint2* h16 = (uint2*)ws;

    if (ws_size >= needA && N <= (1 << 17) && NB <= 1024) {
        unsigned* off    = (unsigned*)(ws + off_b);
        int*      sdst   = (int*)(ws + sdst_b);
        unsigned* binned = (unsigned*)(ws + binned_b);
        unsigned* bcnt   = (unsigned*)(ws + bcnt_b);
        unsigned* bbase  = (unsigned*)(ws + bbase_b);
        unsigned* gcur   = (unsigned*)(ws + gcur_b);

        hipMemsetAsync(bcnt, 0, (size_t)NB * 4, stream);
        gemm_xw<<<ngemm, 256, 0, stream>>>(x, W, nullptr, h16, ei, bcnt, N, E, EPB, NB, 1 | 4);
        scan_buckets<<<1, 256, 0, stream>>>(bcnt, bbase, gcur, NB);
        binA<<<nbt, 256, 0, stream>>>(ei, gcur, binned, E, NB);
        binB<<<NB, 256, 0, stream>>>(binned, bbase, bcnt, off, sdst, N, E, NB);
        node_kernel<<<((size_t)N * 64 + 255) / 256, 256, 0, stream>>>(off, sdst, h16, a, out, N);
    } else if (ws_size >= needB && N <= (1 << 17)) {
        unsigned* off    = (unsigned*)(ws + off_b);
        int*      sdst   = (int*)(ws + sdst_b);
        unsigned* cursor = (unsigned*)(ws + cursor_b);
        unsigned* cnt    = (unsigned*)(ws + cnt_b);
        unsigned* bsum   = (unsigned*)(ws + bsum_b);
        const int nb2 = (N + 2047) / 2048;

        hipMemsetAsync(cnt, 0, (size_t)N * 4, stream);
        gemm_xw<<<ngemm, 256, 0, stream>>>(x, W, nullptr, h16, ei, nullptr, N, E, EPB, NB, 1);
        hist_kernel<<<(E + 255) / 256, 256, 0, stream>>>(ei, cnt, E);
        scan1<<<nb2, 256, 0, stream>>>(cnt, bsum, N);
        scan2<<<1, 128, 0, stream>>>(bsum, off, nb2, N);
        scan3<<<nb2, 256, 0, stream>>>(cnt, bsum, off, cursor, N);
        scatter_kernel<<<(E + 255) / 256, 256, 0, stream>>>(ei, cursor, sdst, E);
        node_kernel<<<((size_t)N * 64 + 255) / 256, 256, 0, stream>>>(off, sdst, h16, a, out, N);
    } else {
        float* h32    = (float*)ws;
        float* rowsum = (float*)(ws + align_up((size_t)N * F_OUT * 4, 256));
        (void)needC;
        hipMemsetAsync(d_out, 0, (size_t)N * F_OUT * sizeof(float), stream);
        hipMemsetAsync(rowsum, 0, (size_t)N * sizeof(float), stream);
        gemm_xw<<<ngemm, 256, 0, stream>>>(x, W, h32, nullptr, ei, nullptr, N, E, EPB, NB, 2);
        edge_kernel<<<2048, 256, 0, stream>>>(ei, h32, a, out, rowsum, E);
        finalize<<<((size_t)N * F_OUT + 255) / 256, 256, 0, stream>>>(out, rowsum, N * F_OUT);
    }
}

// Round 9
// 159.415 us; speedup vs baseline: 3.3615x; 1.1004x over previous
//
#include <hip/hip_runtime.h>
#include <hip/hip_fp16.h>

#define F_IN 128
#define F_OUT 64
#define BIN_TILE 2048
#define BSHIFT 8            // 256 nodes per bucket
#define BNODES 256
#define BCAP 6144u          // per-bucket capacity (mean fill ~4092 at E=1.6M,NB=391; 32-sigma slack)

#define LK_A 0.505f         // leaky(v) = LK_A*v + LK_B*|v| == leaky_relu(v, 0.01)
#define LK_B 0.495f

__device__ __forceinline__ float leaky(float v) {
    return fmaf(LK_B, fabsf(v), LK_A * v);
}

template <int CTRL>
__device__ __forceinline__ float dppadd(float v) {
    return v + __builtin_bit_cast(float,
        __builtin_amdgcn_update_dpp(0, __builtin_bit_cast(int, v), CTRL, 0xf, 0xf, true));
}

// sum across each 8-lane group (pure VALU DPP); every lane gets its group's sum
__device__ __forceinline__ float sum8(float v) {
    v = dppadd<0xB1>(v);    // quad_perm [1,0,3,2]  (xor 1)
    v = dppadd<0x4E>(v);    // quad_perm [2,3,0,1]  (xor 2)
    v = dppadd<0x141>(v);   // row_half_mirror      (xor 7 within 8; bits0-1 already uniform)
    return v;
}

// combine the 8 edge-slots, PRESERVING q (lane&7):
// xor 8  == row_ror:8 (rotate by 8 within 16-lane row), then xor 16, xor 32.
__device__ __forceinline__ float xslot_sum(float v) {
    v = dppadd<0x128>(v);   // row_ror:8  -> lane ^ 8 (q preserved)
    v += __shfl_xor(v, 16);
    v += __shfl_xor(v, 32);
    return v;
}

// Full-wave (64-lane) sum via DPP (plan-C fallback helper)
__device__ __forceinline__ float wave_sum(float v) {
    v += __builtin_bit_cast(float, __builtin_amdgcn_update_dpp(0, __builtin_bit_cast(int, v), 0x111, 0xf, 0xf, true));
    v += __builtin_bit_cast(float, __builtin_amdgcn_update_dpp(0, __builtin_bit_cast(int, v), 0x112, 0xf, 0xf, true));
    v += __builtin_bit_cast(float, __builtin_amdgcn_update_dpp(0, __builtin_bit_cast(int, v), 0x114, 0xf, 0xe, true));
    v += __builtin_bit_cast(float, __builtin_amdgcn_update_dpp(0, __builtin_bit_cast(int, v), 0x118, 0xf, 0xc, true));
    v += __builtin_bit_cast(float, __builtin_amdgcn_update_dpp(0, __builtin_bit_cast(int, v), 0x142, 0xa, 0xf, true));
    v += __builtin_bit_cast(float, __builtin_amdgcn_update_dpp(0, __builtin_bit_cast(int, v), 0x143, 0xc, 0xf, true));
    return __builtin_bit_cast(float, __builtin_amdgcn_readlane(__builtin_bit_cast(int, v), 63));
}

__device__ __forceinline__ void cvt8(const uint4 u, float* g) {
    float2 f;
    f = __half22float2(__builtin_bit_cast(__half2, u.x)); g[0] = f.x; g[1] = f.y;
    f = __half22float2(__builtin_bit_cast(__half2, u.y)); g[2] = f.x; g[3] = f.y;
    f = __half22float2(__builtin_bit_cast(__half2, u.z)); g[4] = f.x; g[5] = f.y;
    f = __half22float2(__builtin_bit_cast(__half2, u.w)); g[6] = f.x; g[7] = f.y;
}

// ---------------- Kernel 1: h = x @ W (64 rows x 64 cols per block, reg-prefetched) ----------------
__global__ __launch_bounds__(256) void gemm_xw(const float* __restrict__ x,
                                               const float* __restrict__ W,
                                               float* __restrict__ h32,
                                               uint2* __restrict__ h16,
                                               int N, int mode) {
    __shared__ float w_lds[F_IN][F_OUT];   // 32 KB
    {
        const float4* Wv = (const float4*)W;
        float4* wl = (float4*)w_lds;
        for (int i = threadIdx.x; i < F_IN * F_OUT / 4; i += 256) wl[i] = Wv[i];
    }
    __syncthreads();

    const int cg = threadIdx.x & 15;   // 4 cols
    const int rs = threadIdx.x >> 4;   // 4 rows
    const int row0 = blockIdx.x * 64 + rs * 4;

    int r[4];
#pragma unroll
    for (int i = 0; i < 4; ++i) { const int rr = row0 + i; r[i] = rr < N ? rr : N - 1; }

    float4 acc[4];
#pragma unroll
    for (int i = 0; i < 4; ++i) acc[i] = make_float4(0.f, 0.f, 0.f, 0.f);

    float4 xc[4];
#pragma unroll
    for (int i = 0; i < 4; ++i) xc[i] = *(const float4*)(x + (size_t)r[i] * F_IN);

    for (int k4 = 0; k4 < 32; ++k4) {
        float4 xn[4];
        if (k4 < 31) {
#pragma unroll
            for (int i = 0; i < 4; ++i)
                xn[i] = *(const float4*)(x + (size_t)r[i] * F_IN + (k4 + 1) * 4);
        }
        float4 wv[4];
#pragma unroll
        for (int kk = 0; kk < 4; ++kk)
            wv[kk] = *(const float4*)&w_lds[k4 * 4 + kk][cg * 4];

#pragma unroll
        for (int i = 0; i < 4; ++i) {
            acc[i].x = fmaf(xc[i].x, wv[0].x, acc[i].x);
            acc[i].y = fmaf(xc[i].x, wv[0].y, acc[i].y);
            acc[i].z = fmaf(xc[i].x, wv[0].z, acc[i].z);
            acc[i].w = fmaf(xc[i].x, wv[0].w, acc[i].w);
            acc[i].x = fmaf(xc[i].y, wv[1].x, acc[i].x);
            acc[i].y = fmaf(xc[i].y, wv[1].y, acc[i].y);
            acc[i].z = fmaf(xc[i].y, wv[1].z, acc[i].z);
            acc[i].w = fmaf(xc[i].y, wv[1].w, acc[i].w);
            acc[i].x = fmaf(xc[i].z, wv[2].x, acc[i].x);
            acc[i].y = fmaf(xc[i].z, wv[2].y, acc[i].y);
            acc[i].z = fmaf(xc[i].z, wv[2].z, acc[i].z);
            acc[i].w = fmaf(xc[i].z, wv[2].w, acc[i].w);
            acc[i].x = fmaf(xc[i].w, wv[3].x, acc[i].x);
            acc[i].y = fmaf(xc[i].w, wv[3].y, acc[i].y);
            acc[i].z = fmaf(xc[i].w, wv[3].z, acc[i].z);
            acc[i].w = fmaf(xc[i].w, wv[3].w, acc[i].w);
        }
        if (k4 < 31) {
#pragma unroll
            for (int i = 0; i < 4; ++i) xc[i] = xn[i];
        }
    }

#pragma unroll
    for (int i = 0; i < 4; ++i) {
        const int rr = row0 + i;
        if (rr < N) {
            if (mode & 2) *(float4*)(h32 + (size_t)rr * F_OUT + cg * 4) = acc[i];
            if (mode & 1) {
                uint2 u;
                u.x = __builtin_bit_cast(unsigned, __floats2half2_rn(acc[i].x, acc[i].y));
                u.y = __builtin_bit_cast(unsigned, __floats2half2_rn(acc[i].z, acc[i].w));
                h16[(size_t)rr * 16 + cg] = u;
            }
        }
    }
}

// ---------------- CSR build: cursor-seeded binning (no pre-count pass) ----------------
__global__ void init_gcur(unsigned* __restrict__ gcur, int NB, unsigned cap) {
    const int i = blockIdx.x * 256 + threadIdx.x;
    if (i < NB) gcur[i] = (unsigned)i * cap;
}

__global__ __launch_bounds__(256) void binA(const int* __restrict__ ei,
                                            unsigned* __restrict__ gcur,
                                            unsigned* __restrict__ binned,
                                            int E, int NB, unsigned cap) {
    __shared__ unsigned lcnt[1024];
    __shared__ unsigned lbase[1024];
    const int t = threadIdx.x;
    for (int i = t; i < NB; i += 256) lcnt[i] = 0;
    __syncthreads();
    const int base = blockIdx.x * BIN_TILE;
    unsigned pk[8], bk[8], rk[8];
#pragma unroll
    for (int i = 0; i < 8; ++i) {
        const int e = base + i * 256 + t;
        if (e < E) {
            const unsigned s = (unsigned)ei[e];
            const unsigned d = (unsigned)ei[E + e];
            bk[i] = s >> BSHIFT;
            pk[i] = ((s & (BNODES - 1u)) << 17) | d;
            rk[i] = atomicAdd(&lcnt[bk[i]], 1u);
        }
    }
    __syncthreads();
    for (int i = t; i < NB; i += 256) {
        const unsigned c = lcnt[i];
        lbase[i] = c ? atomicAdd(&gcur[i], c) : 0u;
    }
    __syncthreads();
#pragma unroll
    for (int i = 0; i < 8; ++i) {
        const int e = base + i * 256 + t;
        if (e < E) {
            const unsigned pos = lbase[bk[i]] + rk[i];
            if (pos < (bk[i] + 1u) * cap) binned[pos] = pk[i];  // OOB-safe (never for this input)
        }
    }
}

// single block: counts from cursors + exclusive scan -> bcnt, bbase
__global__ __launch_bounds__(256) void scan_counts(const unsigned* __restrict__ gcur,
                                                   unsigned* __restrict__ bcnt,
                                                   unsigned* __restrict__ bbase,
                                                   int NB, unsigned cap) {
    __shared__ unsigned v[1024];
    __shared__ unsigned ts[256];
    const int t = threadIdx.x;
    for (int i = t; i < 1024; i += 256) {
        unsigned c = 0;
        if (i < NB) { c = gcur[i] - (unsigned)i * cap; if (c > cap) c = cap; }
        v[i] = c;
    }
    __syncthreads();
    unsigned s = 0;
#pragma unroll
    for (int j = 0; j < 4; ++j) s += v[t * 4 + j];
    ts[t] = s;
    __syncthreads();
    for (int st = 1; st < 256; st <<= 1) {
        const unsigned add = (t >= st) ? ts[t - st] : 0u;
        __syncthreads();
        ts[t] += add;
        __syncthreads();
    }
    unsigned run = (t > 0) ? ts[t - 1] : 0u;
#pragma unroll
    for (int j = 0; j < 4; ++j) {
        const int i = t * 4 + j;
        const unsigned c = v[i];
        if (i < NB) { bcnt[i] = c; bbase[i] = run; }
        run += c;
    }
}

// one block per 256-node bucket: LDS hist + scan -> off[]; LDS-staged scatter -> sdst[]
__global__ __launch_bounds__(256) void binB(const unsigned* __restrict__ binned,
                                            const unsigned* __restrict__ bbase,
                                            const unsigned* __restrict__ bcnt,
                                            unsigned* __restrict__ off,
                                            int* __restrict__ sdst,
                                            int N, int NB, unsigned cap) {
    __shared__ unsigned stg[BCAP];       // 24 KB
    __shared__ unsigned ncnt[BNODES];
    __shared__ unsigned ts[256];
    const int b = blockIdx.x;
    const int t = threadIdx.x;
    const unsigned src0 = (unsigned)b * cap;
    const unsigned beg = bbase[b];
    unsigned sz = bcnt[b]; if (sz > BCAP) sz = BCAP;

    ncnt[t] = 0;
    for (unsigned i = t; i < sz; i += 256) stg[i] = binned[src0 + i];
    __syncthreads();

    for (unsigned i = t; i < sz; i += 256) atomicAdd(&ncnt[stg[i] >> 17], 1u);
    __syncthreads();

    const unsigned myc = ncnt[t];
    ts[t] = myc;
    __syncthreads();
    for (int st = 1; st < 256; st <<= 1) {
        const unsigned add = (t >= st) ? ts[t - st] : 0u;
        __syncthreads();
        ts[t] += add;
        __syncthreads();
    }
    const unsigned excl = ts[t] - myc;
    ncnt[t] = excl;                      // becomes cursor
    const int g = (b << BSHIFT) + t;
    if (g < N) off[g] = beg + excl;
    if (b == NB - 1 && t == 0) off[N] = beg + ts[255];
    __syncthreads();

    for (unsigned i = t; i < sz; i += 256) {
        const unsigned p = stg[i];
        const unsigned pos = atomicAdd(&ncnt[p >> 17], 1u);
        sdst[beg + pos] = (int)(p & 0x1FFFFu);
    }
}

// ---------------- Fused per-node kernel: 8 edges/wave (8 slots x 8 lanes x 8 fp16), persistent ----------------
__global__ __launch_bounds__(256) void node_kernel(const unsigned* __restrict__ off,
                                                   const int* __restrict__ sdst,
                                                   const uint2* __restrict__ h16v,
                                                   const float* __restrict__ a,
                                                   float* __restrict__ out, int N) {
    const int lane = threadIdx.x & 63;
    const int slot = lane >> 3;          // edge slot 0..7
    const int q    = lane & 7;           // feature octet 0..7
    const char* h16 = (const char*)h16v;

    float A0[8], A1[8], A2[8], A3[8];
#pragma unroll
    for (int f = 0; f < 8; ++f) {
        A0[f] = a[q * 8 + f];
        A1[f] = a[64 + q * 8 + f];
        A2[f] = a[128 + q * 8 + f];
        A3[f] = a[192 + q * 8 + f];
    }
    float b1[8], a2b[8], a3b[8], a0m[8];
#pragma unroll
    for (int f = 0; f < 8; ++f) {
        b1[f]  = fmaf(LK_A, A2[f] - A3[f], A1[f]);
        a2b[f] = LK_B * A2[f];
        a3b[f] = LK_B * A3[f];
        a0m[f] = fmaf(LK_A, A2[f] + A3[f], A0[f]);
    }

    const int wid = (int)((blockIdx.x * 256u + threadIdx.x) >> 6);
    const int nw  = (int)((gridDim.x * 256u) >> 6);

    for (int node = wid; node < N; node += nw) {
        const int beg = (int)__builtin_amdgcn_readfirstlane((int)off[node]);
        const int end = (int)__builtin_amdgcn_readfirstlane((int)off[node + 1]);

        float hs[8];
        {
            const uint4 u = *(const uint4*)(h16 + ((size_t)node << 7) + q * 16);
            cvt8(u, hs);
        }
        float csp = 0.f;
#pragma unroll
        for (int f = 0; f < 8; ++f) csp = fmaf(hs[f], a0m[f], csp);
        const float cs = sum8(csp);   // identical in every 8-group

        float acc[8];
#pragma unroll
        for (int f = 0; f < 8; ++f) acc[f] = 0.f;
        float rsum = 0.f;

        if (beg < end) {
            const int endm1 = end - 1;
            int e0 = beg + slot; if (e0 > endm1) e0 = endm1;
            int dA = sdst[e0];
            uint4 uA = *(const uint4*)(h16 + ((size_t)dA << 7) + q * 16);
            int dB = dA;
            if (beg + 8 < end) { int e1 = beg + 8 + slot; if (e1 > endm1) e1 = endm1; dB = sdst[e1]; }
            uint4 uB = *(const uint4*)(h16 + ((size_t)dB << 7) + q * 16);
            int dC = dB;
            if (beg + 16 < end) { int e2 = beg + 16 + slot; if (e2 > endm1) e2 = endm1; dC = sdst[e2]; }

            for (int base = beg; base < end; base += 8) {
                uint4 uC = uB;
                int dD = dC;
                if (base + 16 < end)
                    uC = *(const uint4*)(h16 + ((size_t)dC << 7) + q * 16);   // gather 2 chunks ahead
                if (base + 24 < end) { int e3 = base + 24 + slot; if (e3 > endm1) e3 = endm1; dD = sdst[e3]; }

                float g[8];
                cvt8(uA, g);
                float p0 = 0.f, p1 = 0.f;
#pragma unroll
                for (int f = 0; f < 8; f += 2) {
                    const float sa0 = hs[f] + g[f],       sb0 = hs[f] - g[f];
                    const float sa1 = hs[f + 1] + g[f + 1], sb1 = hs[f + 1] - g[f + 1];
                    p0 = fmaf(g[f],     b1[f],     p0);
                    p1 = fmaf(g[f + 1], b1[f + 1], p1);
                    p0 = fmaf(fabsf(sa0), a2b[f],     p0);
                    p1 = fmaf(fabsf(sa1), a2b[f + 1], p1);
                    p0 = fmaf(fabsf(sb0), a3b[f],     p0);
                    p1 = fmaf(fabsf(sb1), a3b[f + 1], p1);
                }
                const float R = sum8(p0 + p1);   // per-slot edge score part

                float e = __expf(-leaky(cs + R));
                e = (base + slot < end) ? e : 0.f;
#pragma unroll
                for (int f = 0; f < 8; ++f) acc[f] = fmaf(e, g[f], acc[f]);
                rsum += e;

                uA = uB; uB = uC; dC = dD;
            }
        }

#pragma unroll
        for (int f = 0; f < 8; ++f) acc[f] = xslot_sum(acc[f]);
        rsum = xslot_sum(rsum);

        if (slot == 0) {
            const float inv = 1.f / (rsum + 1e-16f);
            float4 o0, o1;
            o0.x = acc[0] * inv; o0.y = acc[1] * inv; o0.z = acc[2] * inv; o0.w = acc[3] * inv;
            o1.x = acc[4] * inv; o1.y = acc[5] * inv; o1.z = acc[6] * inv; o1.w = acc[7] * inv;
            float* orow = out + (size_t)node * F_OUT + q * 8;
            *(float4*)orow = o0;
            *(float4*)(orow + 4) = o1;
        }
    }
}

// ---------------- Plan B: old CSR build (hist + scans + scatter) ----------------
__global__ __launch_bounds__(256) void hist_kernel(const int* __restrict__ ei,
                                                   unsigned* __restrict__ cnt, int E) {
    const int e = blockIdx.x * 256 + threadIdx.x;
    if (e < E) atomicAdd(&cnt[ei[e]], 1u);
}

__global__ __launch_bounds__(256) void scan1(const unsigned* __restrict__ cnt,
                                             unsigned* __restrict__ bsum, int n) {
    __shared__ unsigned lds[256];
    const int t = threadIdx.x;
    const int base = blockIdx.x * 2048 + t * 8;
    unsigned s = 0;
#pragma unroll
    for (int i = 0; i < 8; ++i) { const int idx = base + i; if (idx < n) s += cnt[idx]; }
    lds[t] = s; __syncthreads();
    for (int st = 128; st > 0; st >>= 1) {
        if (t < st) lds[t] += lds[t + st];
        __syncthreads();
    }
    if (t == 0) bsum[blockIdx.x] = lds[0];
}

__global__ __launch_bounds__(128) void scan2(unsigned* __restrict__ bsum,
                                             unsigned* __restrict__ off, int nb, int n) {
    __shared__ unsigned lds[128];
    const int t = threadIdx.x;
    if (t < nb) lds[t] = bsum[t];
    __syncthreads();
    if (t == 0) {
        unsigned run = 0;
        for (int i = 0; i < nb; ++i) { const unsigned v = lds[i]; lds[i] = run; run += v; }
        off[n] = run;
    }
    __syncthreads();
    if (t < nb) bsum[t] = lds[t];
}

__global__ __launch_bounds__(256) void scan3(const unsigned* __restrict__ cnt,
                                             const unsigned* __restrict__ bsum,
                                             unsigned* __restrict__ off,
                                             unsigned* __restrict__ cursor, int n) {
    __shared__ unsigned lds[256];
    const int t = threadIdx.x;
    const int base = blockIdx.x * 2048 + t * 8;
    unsigned v[8]; unsigned s = 0;
#pragma unroll
    for (int i = 0; i < 8; ++i) { const int idx = base + i; v[i] = (idx < n) ? cnt[idx] : 0u; s += v[i]; }
    lds[t] = s; __syncthreads();
    for (int st = 1; st < 256; st <<= 1) {
        const unsigned add = (t >= st) ? lds[t - st] : 0u;
        __syncthreads();
        lds[t] += add;
        __syncthreads();
    }
    unsigned excl = (t > 0 ? lds[t - 1] : 0u) + bsum[blockIdx.x];
#pragma unroll
    for (int i = 0; i < 8; ++i) {
        const int idx = base + i;
        if (idx < n) { off[idx] = excl; cursor[idx] = excl; excl += v[i]; }
    }
}

__global__ __launch_bounds__(256) void scatter_kernel(const int* __restrict__ ei,
                                                      unsigned* __restrict__ cursor,
                                                      int* __restrict__ sdst, int E) {
    const int e = blockIdx.x * 256 + threadIdx.x;
    if (e >= E) return;
    const int s = ei[e];
    const int d = ei[E + e];
    const unsigned pos = atomicAdd(&cursor[s], 1u);
    sdst[pos] = d;
}

// ---------------- Plan C: atomic fallback ----------------
__device__ __forceinline__ float edge_part(float hs, float hd, float a1, float a2, float a3) {
    float p = hd * a1;
    p = fmaf(leaky(hs + hd), a2, p);
    p = fmaf(leaky(hs - hd), a3, p);
    return p;
}

__global__ __launch_bounds__(256) void edge_kernel(const int* __restrict__ ei,
                                                   const float* __restrict__ h,
                                                   const float* __restrict__ a,
                                                   float* __restrict__ hprime,
                                                   float* __restrict__ rowsum,
                                                   int E) {
    const int lane = threadIdx.x & 63;
    const int wave = (int)((blockIdx.x * blockDim.x + threadIdx.x) >> 6);
    const int nwaves = (int)((gridDim.x * blockDim.x) >> 6);
    const float a0 = a[lane], a1 = a[64 + lane], a2 = a[128 + lane], a3 = a[192 + lane];
    for (int e = wave; e < E; e += nwaves) {
        const int s = ei[e];
        const int d = ei[E + e];
        const float hs = h[(size_t)s * F_OUT + lane];
        const float hd = h[(size_t)d * F_OUT + lane];
        const float part = wave_sum(hs * a0 + edge_part(hs, hd, a1, a2, a3));
        const float ee = __expf(-leaky(part));
        atomicAdd(&hprime[(size_t)s * F_OUT + lane], ee * hd);
        if (lane == 0) atomicAdd(&rowsum[s], ee);
    }
}

__global__ __launch_bounds__(256) void finalize(float* __restrict__ out,
                                                const float* __restrict__ rowsum,
                                                int total) {
    const int i = blockIdx.x * blockDim.x + threadIdx.x;
    if (i < total) out[i] = out[i] / (rowsum[i >> 6] + 1e-16f);
}

static inline size_t align_up(size_t v, size_t a) { return (v + a - 1) & ~(a - 1); }

extern "C" void kernel_launch(void* const* d_in, const int* in_sizes, int n_in,
                              void* d_out, int out_size, void* d_ws, size_t ws_size,
                              hipStream_t stream) {
    const float* x  = (const float*)d_in[0];
    const int*   ei = (const int*)d_in[1];
    const float* W  = (const float*)d_in[2];
    const float* a  = (const float*)d_in[3];

    const int N = in_sizes[0] / F_IN;
    const int E = in_sizes[1] / 2;
    float* out = (float*)d_out;

    const int NB = (N + BNODES - 1) >> BSHIFT;
    const int ngemm = (N + 63) / 64;
    const int nbt = (E + BIN_TILE - 1) / BIN_TILE;
    const unsigned meanFill = (NB > 0) ? (unsigned)(E / NB) : 0u;

    char* ws = (char*)d_ws;
    const size_t szh16  = align_up((size_t)N * F_OUT * 2, 256);
    const size_t szoff  = align_up(((size_t)N + 1) * 4, 256);
    const size_t szedge = align_up((size_t)E * 4 + 64, 256);
    const size_t szbin  = align_up((size_t)NB * BCAP * 4 + 64, 256);

    // common prefix: h16 | off | sdst
    const size_t off_b  = szh16;
    const size_t sdst_b = off_b + szoff;
    // plan A tail: binned | gcur | bcnt | bbase
    const size_t binned_b = sdst_b + szedge;
    const size_t gcur_b   = binned_b + szbin;
    const size_t bcnt_b   = gcur_b + 4096;
    const size_t bbase_b  = bcnt_b + 4096;
    const size_t needA    = bbase_b + 4096;
    // plan B tail: cursor | cnt | bsum
    const size_t cursor_b = sdst_b + szedge;
    const size_t cnt_b    = cursor_b + align_up((size_t)N * 4, 256);
    const size_t bsum_b   = cnt_b + align_up((size_t)N * 4, 256);
    const size_t needB    = bsum_b + 4096;

    uint2* h16 = (uint2*)ws;
    const int nodeBlocks = 2048;

    if (ws_size >= needA && N <= (1 << 17) && NB <= 1024 && meanFill <= (BCAP * 3u) / 4u) {
        unsigned* off    = (unsigned*)(ws + off_b);
        int*      sdst   = (int*)(ws + sdst_b);
        unsigned* binned = (unsigned*)(ws + binned_b);
        unsigned* gcur   = (unsigned*)(ws + gcur_b);
        unsigned* bcnt   = (unsigned*)(ws + bcnt_b);
        unsigned* bbase  = (unsigned*)(ws + bbase_b);

        init_gcur<<<(NB + 255) / 256, 256, 0, stream>>>(gcur, NB, BCAP);
        gemm_xw<<<ngemm, 256, 0, stream>>>(x, W, nullptr, h16, N, 1);
        binA<<<nbt, 256, 0, stream>>>(ei, gcur, binned, E, NB, BCAP);
        scan_counts<<<1, 256, 0, stream>>>(gcur, bcnt, bbase, NB, BCAP);
        binB<<<NB, 256, 0, stream>>>(binned, bbase, bcnt, off, sdst, N, NB, BCAP);
        node_kernel<<<nodeBlocks, 256, 0, stream>>>(off, sdst, h16, a, out, N);
    } else if (ws_size >= needB && N <= (1 << 17)) {
        unsigned* off    = (unsigned*)(ws + off_b);
        int*      sdst   = (int*)(ws + sdst_b);
        unsigned* cursor = (unsigned*)(ws + cursor_b);
        unsigned* cnt    = (unsigned*)(ws + cnt_b);
        unsigned* bsum   = (unsigned*)(ws + bsum_b);
        const int nb2 = (N + 2047) / 2048;

        hipMemsetAsync(cnt, 0, (size_t)N * 4, stream);
        gemm_xw<<<ngemm, 256, 0, stream>>>(x, W, nullptr, h16, N, 1);
        hist_kernel<<<(E + 255) / 256, 256, 0, stream>>>(ei, cnt, E);
        scan1<<<nb2, 256, 0, stream>>>(cnt, bsum, N);
        scan2<<<1, 128, 0, stream>>>(bsum, off, nb2, N);
        scan3<<<nb2, 256, 0, stream>>>(cnt, bsum, off, cursor, N);
        scatter_kernel<<<(E + 255) / 256, 256, 0, stream>>>(ei, cursor, sdst, E);
        node_kernel<<<nodeBlocks, 256, 0, stream>>>(off, sdst, h16, a, out, N);
    } else {
        float* h32    = (float*)ws;
        float* rowsum = (float*)(ws + align_up((size_t)N * F_OUT * 4, 256));
        hipMemsetAsync(d_out, 0, (size_t)N * F_OUT * sizeof(float), stream);
        hipMemsetAsync(rowsum, 0, (size_t)N * sizeof(float), stream);
        gemm_xw<<<ngemm, 256, 0, stream>>>(x, W, h32, nullptr, N, 2);
        edge_kernel<<<2048, 256, 0, stream>>>(ei, h32, a, out, rowsum, E);
        finalize<<<((size_t)N * F_OUT + 255) / 256, 256, 0, stream>>>(out, rowsum, N * F_OUT);
    }
}

// Round 10
// 144.621 us; speedup vs baseline: 3.7054x; 1.1023x over previous
//
#include <hip/hip_runtime.h>
#include <hip/hip_fp16.h>

#define F_IN 128
#define F_OUT 64
#define BIN_TILE 2048
#define BSHIFT 8            // 256 nodes per bucket
#define BNODES 256
#define BCAP 6144u          // per-bucket capacity (mean fill ~4092 at E=1.6M,NB=391)

#define LK_A 0.505f         // leaky(v) = LK_A*v + LK_B*|v| == leaky_relu(v, 0.01)
#define LK_B 0.495f

__device__ __forceinline__ float leaky(float v) {
    return fmaf(LK_B, fabsf(v), LK_A * v);
}

template <int CTRL>
__device__ __forceinline__ float dppadd(float v) {
    return v + __builtin_bit_cast(float,
        __builtin_amdgcn_update_dpp(0, __builtin_bit_cast(int, v), CTRL, 0xf, 0xf, true));
}

// sum across each 8-lane group (pure VALU DPP); every lane gets its group's sum
__device__ __forceinline__ float sum8(float v) {
    v = dppadd<0xB1>(v);    // quad_perm [1,0,3,2]  (xor 1)
    v = dppadd<0x4E>(v);    // quad_perm [2,3,0,1]  (xor 2)
    v = dppadd<0x141>(v);   // row_half_mirror      (xor 7 within 8)
    return v;
}

// combine the 4 edge-slots of a 32-lane HALF, preserving q (lane&7):
// lane^8 via row_ror:8 (rotate within 16-lane row), then xor16 (stays in half).
__device__ __forceinline__ float xslot_sum2(float v) {
    v = dppadd<0x128>(v);   // row_ror:8 -> lane ^ 8 (q preserved)
    v += __shfl_xor(v, 16);
    return v;
}

// Full-wave (64-lane) sum via DPP (plan-C fallback helper)
__device__ __forceinline__ float wave_sum(float v) {
    v += __builtin_bit_cast(float, __builtin_amdgcn_update_dpp(0, __builtin_bit_cast(int, v), 0x111, 0xf, 0xf, true));
    v += __builtin_bit_cast(float, __builtin_amdgcn_update_dpp(0, __builtin_bit_cast(int, v), 0x112, 0xf, 0xf, true));
    v += __builtin_bit_cast(float, __builtin_amdgcn_update_dpp(0, __builtin_bit_cast(int, v), 0x114, 0xf, 0xe, true));
    v += __builtin_bit_cast(float, __builtin_amdgcn_update_dpp(0, __builtin_bit_cast(int, v), 0x118, 0xf, 0xc, true));
    v += __builtin_bit_cast(float, __builtin_amdgcn_update_dpp(0, __builtin_bit_cast(int, v), 0x142, 0xa, 0xf, true));
    v += __builtin_bit_cast(float, __builtin_amdgcn_update_dpp(0, __builtin_bit_cast(int, v), 0x143, 0xc, 0xf, true));
    return __builtin_bit_cast(float, __builtin_amdgcn_readlane(__builtin_bit_cast(int, v), 63));
}

__device__ __forceinline__ void cvt8(const uint4 u, float* g) {
    float2 f;
    f = __half22float2(__builtin_bit_cast(__half2, u.x)); g[0] = f.x; g[1] = f.y;
    f = __half22float2(__builtin_bit_cast(__half2, u.y)); g[2] = f.x; g[3] = f.y;
    f = __half22float2(__builtin_bit_cast(__half2, u.z)); g[4] = f.x; g[5] = f.y;
    f = __half22float2(__builtin_bit_cast(__half2, u.w)); g[6] = f.x; g[7] = f.y;
}

// ---------------- Kernel 1: h = x @ W (64 rows x 64 cols per block); block 0 also seeds gcur ----------------
__global__ __launch_bounds__(256) void gemm_xw(const float* __restrict__ x,
                                               const float* __restrict__ W,
                                               float* __restrict__ h32,
                                               uint2* __restrict__ h16,
                                               unsigned* __restrict__ gcur,
                                               int N, int NB, unsigned cap, int mode) {
    if (gcur && blockIdx.x == 0)
        for (int i = threadIdx.x; i < NB; i += 256) gcur[i] = (unsigned)i * cap;

    __shared__ float w_lds[F_IN][F_OUT];   // 32 KB
    {
        const float4* Wv = (const float4*)W;
        float4* wl = (float4*)w_lds;
        for (int i = threadIdx.x; i < F_IN * F_OUT / 4; i += 256) wl[i] = Wv[i];
    }
    __syncthreads();

    const int cg = threadIdx.x & 15;   // 4 cols
    const int rs = threadIdx.x >> 4;   // 4 rows
    const int row0 = blockIdx.x * 64 + rs * 4;

    int r[4];
#pragma unroll
    for (int i = 0; i < 4; ++i) { const int rr = row0 + i; r[i] = rr < N ? rr : N - 1; }

    float4 acc[4];
#pragma unroll
    for (int i = 0; i < 4; ++i) acc[i] = make_float4(0.f, 0.f, 0.f, 0.f);

    float4 xc[4];
#pragma unroll
    for (int i = 0; i < 4; ++i) xc[i] = *(const float4*)(x + (size_t)r[i] * F_IN);

    for (int k4 = 0; k4 < 32; ++k4) {
        float4 xn[4];
        if (k4 < 31) {
#pragma unroll
            for (int i = 0; i < 4; ++i)
                xn[i] = *(const float4*)(x + (size_t)r[i] * F_IN + (k4 + 1) * 4);
        }
        float4 wv[4];
#pragma unroll
        for (int kk = 0; kk < 4; ++kk)
            wv[kk] = *(const float4*)&w_lds[k4 * 4 + kk][cg * 4];

#pragma unroll
        for (int i = 0; i < 4; ++i) {
            acc[i].x = fmaf(xc[i].x, wv[0].x, acc[i].x);
            acc[i].y = fmaf(xc[i].x, wv[0].y, acc[i].y);
            acc[i].z = fmaf(xc[i].x, wv[0].z, acc[i].z);
            acc[i].w = fmaf(xc[i].x, wv[0].w, acc[i].w);
            acc[i].x = fmaf(xc[i].y, wv[1].x, acc[i].x);
            acc[i].y = fmaf(xc[i].y, wv[1].y, acc[i].y);
            acc[i].z = fmaf(xc[i].y, wv[1].z, acc[i].z);
            acc[i].w = fmaf(xc[i].y, wv[1].w, acc[i].w);
            acc[i].x = fmaf(xc[i].z, wv[2].x, acc[i].x);
            acc[i].y = fmaf(xc[i].z, wv[2].y, acc[i].y);
            acc[i].z = fmaf(xc[i].z, wv[2].z, acc[i].z);
            acc[i].w = fmaf(xc[i].z, wv[2].w, acc[i].w);
            acc[i].x = fmaf(xc[i].w, wv[3].x, acc[i].x);
            acc[i].y = fmaf(xc[i].w, wv[3].y, acc[i].y);
            acc[i].z = fmaf(xc[i].w, wv[3].z, acc[i].z);
            acc[i].w = fmaf(xc[i].w, wv[3].w, acc[i].w);
        }
        if (k4 < 31) {
#pragma unroll
            for (int i = 0; i < 4; ++i) xc[i] = xn[i];
        }
    }

#pragma unroll
    for (int i = 0; i < 4; ++i) {
        const int rr = row0 + i;
        if (rr < N) {
            if (mode & 2) *(float4*)(h32 + (size_t)rr * F_OUT + cg * 4) = acc[i];
            if (mode & 1) {
                uint2 u;
                u.x = __builtin_bit_cast(unsigned, __floats2half2_rn(acc[i].x, acc[i].y));
                u.y = __builtin_bit_cast(unsigned, __floats2half2_rn(acc[i].z, acc[i].w));
                h16[(size_t)rr * 16 + cg] = u;
            }
        }
    }
}

// ---------------- CSR build: cursor-seeded binning ----------------
__global__ __launch_bounds__(256) void binA(const int* __restrict__ ei,
                                            unsigned* __restrict__ gcur,
                                            unsigned* __restrict__ binned,
                                            int E, int NB, unsigned cap) {
    __shared__ unsigned lcnt[1024];
    __shared__ unsigned lbase[1024];
    const int t = threadIdx.x;
    for (int i = t; i < NB; i += 256) lcnt[i] = 0;
    __syncthreads();
    const int base = blockIdx.x * BIN_TILE;
    unsigned pk[8], bk[8], rk[8];
#pragma unroll
    for (int i = 0; i < 8; ++i) {
        const int e = base + i * 256 + t;
        if (e < E) {
            const unsigned s = (unsigned)ei[e];
            const unsigned d = (unsigned)ei[E + e];
            bk[i] = s >> BSHIFT;
            pk[i] = ((s & (BNODES - 1u)) << 17) | d;
            rk[i] = atomicAdd(&lcnt[bk[i]], 1u);
        }
    }
    __syncthreads();
    for (int i = t; i < NB; i += 256) {
        const unsigned c = lcnt[i];
        lbase[i] = c ? atomicAdd(&gcur[i], c) : 0u;
    }
    __syncthreads();
#pragma unroll
    for (int i = 0; i < 8; ++i) {
        const int e = base + i * 256 + t;
        if (e < E) {
            const unsigned pos = lbase[bk[i]] + rk[i];
            if (pos < (bk[i] + 1u) * cap) binned[pos] = pk[i];
        }
    }
}

// single block: counts from cursors + exclusive scan -> bcnt, bbase
__global__ __launch_bounds__(256) void scan_counts(const unsigned* __restrict__ gcur,
                                                   unsigned* __restrict__ bcnt,
                                                   unsigned* __restrict__ bbase,
                                                   int NB, unsigned cap) {
    __shared__ unsigned v[1024];
    __shared__ unsigned ts[256];
    const int t = threadIdx.x;
    for (int i = t; i < 1024; i += 256) {
        unsigned c = 0;
        if (i < NB) { c = gcur[i] - (unsigned)i * cap; if (c > cap) c = cap; }
        v[i] = c;
    }
    __syncthreads();
    unsigned s = 0;
#pragma unroll
    for (int j = 0; j < 4; ++j) s += v[t * 4 + j];
    ts[t] = s;
    __syncthreads();
    for (int st = 1; st < 256; st <<= 1) {
        const unsigned add = (t >= st) ? ts[t - st] : 0u;
        __syncthreads();
        ts[t] += add;
        __syncthreads();
    }
    unsigned run = (t > 0) ? ts[t - 1] : 0u;
#pragma unroll
    for (int j = 0; j < 4; ++j) {
        const int i = t * 4 + j;
        const unsigned c = v[i];
        if (i < NB) { bcnt[i] = c; bbase[i] = run; }
        run += c;
    }
}

// one block per 256-node bucket: LDS hist + scan -> off[]; LDS-staged scatter -> sdst[]
__global__ __launch_bounds__(256) void binB(const unsigned* __restrict__ binned,
                                            const unsigned* __restrict__ bbase,
                                            const unsigned* __restrict__ bcnt,
                                            unsigned* __restrict__ off,
                                            int* __restrict__ sdst,
                                            int N, int NB, unsigned cap) {
    __shared__ unsigned stg[BCAP];       // 24 KB
    __shared__ unsigned ncnt[BNODES];
    __shared__ unsigned ts[256];
    const int b = blockIdx.x;
    const int t = threadIdx.x;
    const unsigned src0 = (unsigned)b * cap;
    const unsigned beg = bbase[b];
    unsigned sz = bcnt[b]; if (sz > BCAP) sz = BCAP;

    ncnt[t] = 0;
    for (unsigned i = t; i < sz; i += 256) stg[i] = binned[src0 + i];
    __syncthreads();

    for (unsigned i = t; i < sz; i += 256) atomicAdd(&ncnt[stg[i] >> 17], 1u);
    __syncthreads();

    const unsigned myc = ncnt[t];
    ts[t] = myc;
    __syncthreads();
    for (int st = 1; st < 256; st <<= 1) {
        const unsigned add = (t >= st) ? ts[t - st] : 0u;
        __syncthreads();
        ts[t] += add;
        __syncthreads();
    }
    const unsigned excl = ts[t] - myc;
    ncnt[t] = excl;                      // becomes cursor
    const int g = (b << BSHIFT) + t;
    if (g < N) off[g] = beg + excl;
    if (b == NB - 1 && t == 0) off[N] = beg + ts[255];
    __syncthreads();

    for (unsigned i = t; i < sz; i += 256) {
        const unsigned p = stg[i];
        const unsigned pos = atomicAdd(&ncnt[p >> 17], 1u);
        sdst[beg + pos] = (int)(p & 0x1FFFFu);
    }
}

// ---------------- Fused per-node kernel: 2 nodes/wave (32-lane halves), 4 slots x 8 q each ----------------
__global__ __launch_bounds__(256) void node_kernel(const unsigned* __restrict__ off,
                                                   const int* __restrict__ sdst,
                                                   const uint2* __restrict__ h16v,
                                                   const float* __restrict__ a,
                                                   float* __restrict__ out, int N) {
    const int lane  = threadIdx.x & 63;
    const int half  = lane >> 5;           // node sub-slot 0/1
    const int slot4 = (lane >> 3) & 3;     // edge slot 0..3 within half
    const int q     = lane & 7;            // feature octet 0..7
    const char* h16 = (const char*)h16v;

    float b1[8], a2b[8], a3b[8], a0m[8];
#pragma unroll
    for (int f = 0; f < 8; ++f) {
        const float A0 = a[q * 8 + f];
        const float A1 = a[64 + q * 8 + f];
        const float A2 = a[128 + q * 8 + f];
        const float A3 = a[192 + q * 8 + f];
        b1[f]  = fmaf(LK_A, A2 - A3, A1);
        a2b[f] = LK_B * A2;
        a3b[f] = LK_B * A3;
        a0m[f] = fmaf(LK_A, A2 + A3, A0);
    }

    const int wid = (int)((blockIdx.x * 256u + threadIdx.x) >> 6);
    const int nw  = (int)((gridDim.x * 256u) >> 6);

    for (int pr = wid; pr * 2 < N; pr += nw) {
        const int node = pr * 2 + half;             // per-half node
        const int nc = (node < N) ? node : N - 1;
        const int beg = (int)off[nc];
        const int len = (node < N) ? ((int)off[nc + 1] - beg) : 0;

        float hs[8];
        {
            const uint4 u = *(const uint4*)(h16 + ((size_t)nc << 7) + q * 16);
            cvt8(u, hs);
        }
        float csp = 0.f;
#pragma unroll
        for (int f = 0; f < 8; ++f) csp = fmaf(hs[f], a0m[f], csp);
        const float cs = sum8(csp);

        // max chunks across the two halves (len uniform within each half)
        const int lenO = __shfl_xor(len, 32);
        const int ml = (len > lenO) ? len : lenO;

        float acc[8];
#pragma unroll
        for (int f = 0; f < 8; ++f) acc[f] = 0.f;
        float rsum = 0.f;

        const int lm1 = (len > 0) ? len - 1 : 0;
        int dA = 0;
        if (len > 0) { int e0 = slot4;      if (e0 > lm1) e0 = lm1; dA = sdst[beg + e0]; }
        uint4 uA = *(const uint4*)(h16 + ((size_t)dA << 7) + q * 16);
        int dB = dA;
        if (len > 4)  { int e1 = 4 + slot4;  if (e1 > lm1) e1 = lm1; dB = sdst[beg + e1]; }
        uint4 uB = *(const uint4*)(h16 + ((size_t)dB << 7) + q * 16);
        int dC = dB;
        if (len > 8)  { int e2 = 8 + slot4;  if (e2 > lm1) e2 = lm1; dC = sdst[beg + e2]; }

        for (int cb = 0; cb < ml; cb += 4) {
            uint4 uC = uB;
            int dD = dC;
            if (cb + 8 < len)
                uC = *(const uint4*)(h16 + ((size_t)dC << 7) + q * 16);   // gather 2 chunks ahead
            if (cb + 12 < len) { int e3 = cb + 12 + slot4; if (e3 > lm1) e3 = lm1; dD = sdst[beg + e3]; }

            float g[8];
            cvt8(uA, g);
            float p0 = 0.f, p1 = 0.f;
#pragma unroll
            for (int f = 0; f < 8; f += 2) {
                const float sa0 = hs[f] + g[f],         sb0 = hs[f] - g[f];
                const float sa1 = hs[f + 1] + g[f + 1], sb1 = hs[f + 1] - g[f + 1];
                p0 = fmaf(g[f],     b1[f],     p0);
                p1 = fmaf(g[f + 1], b1[f + 1], p1);
                p0 = fmaf(fabsf(sa0), a2b[f],     p0);
                p1 = fmaf(fabsf(sa1), a2b[f + 1], p1);
                p0 = fmaf(fabsf(sb0), a3b[f],     p0);
                p1 = fmaf(fabsf(sb1), a3b[f + 1], p1);
            }
            const float R = sum8(p0 + p1);   // per-slot edge score part

            float e = __expf(-leaky(cs + R));
            e = (cb + slot4 < len) ? e : 0.f;
#pragma unroll
            for (int f = 0; f < 8; ++f) acc[f] = fmaf(e, g[f], acc[f]);
            rsum += e;

            uA = uB; uB = uC; dC = dD;
        }

#pragma unroll
        for (int f = 0; f < 8; ++f) acc[f] = xslot_sum2(acc[f]);
        rsum = xslot_sum2(rsum);

        if (slot4 == 0 && node < N) {
            const float inv = 1.f / (rsum + 1e-16f);
            float4 o0, o1;
            o0.x = acc[0] * inv; o0.y = acc[1] * inv; o0.z = acc[2] * inv; o0.w = acc[3] * inv;
            o1.x = acc[4] * inv; o1.y = acc[5] * inv; o1.z = acc[6] * inv; o1.w = acc[7] * inv;
            float* orow = out + (size_t)node * F_OUT + q * 8;
            *(float4*)orow = o0;
            *(float4*)(orow + 4) = o1;
        }
    }
}

// ---------------- Plan B: old CSR build (hist + scans + scatter) ----------------
__global__ __launch_bounds__(256) void hist_kernel(const int* __restrict__ ei,
                                                   unsigned* __restrict__ cnt, int E) {
    const int e = blockIdx.x * 256 + threadIdx.x;
    if (e < E) atomicAdd(&cnt[ei[e]], 1u);
}

__global__ __launch_bounds__(256) void scan1(const unsigned* __restrict__ cnt,
                                             unsigned* __restrict__ bsum, int n) {
    __shared__ unsigned lds[256];
    const int t = threadIdx.x;
    const int base = blockIdx.x * 2048 + t * 8;
    unsigned s = 0;
#pragma unroll
    for (int i = 0; i < 8; ++i) { const int idx = base + i; if (idx < n) s += cnt[idx]; }
    lds[t] = s; __syncthreads();
    for (int st = 128; st > 0; st >>= 1) {
        if (t < st) lds[t] += lds[t + st];
        __syncthreads();
    }
    if (t == 0) bsum[blockIdx.x] = lds[0];
}

__global__ __launch_bounds__(128) void scan2(unsigned* __restrict__ bsum,
                                             unsigned* __restrict__ off, int nb, int n) {
    __shared__ unsigned lds[128];
    const int t = threadIdx.x;
    if (t < nb) lds[t] = bsum[t];
    __syncthreads();
    if (t == 0) {
        unsigned run = 0;
        for (int i = 0; i < nb; ++i) { const unsigned v = lds[i]; lds[i] = run; run += v; }
        off[n] = run;
    }
    __syncthreads();
    if (t < nb) bsum[t] = lds[t];
}

__global__ __launch_bounds__(256) void scan3(const unsigned* __restrict__ cnt,
                                             const unsigned* __restrict__ bsum,
                                             unsigned* __restrict__ off,
                                             unsigned* __restrict__ cursor, int n) {
    __shared__ unsigned lds[256];
    const int t = threadIdx.x;
    const int base = blockIdx.x * 2048 + t * 8;
    unsigned v[8]; unsigned s = 0;
#pragma unroll
    for (int i = 0; i < 8; ++i) { const int idx = base + i; v[i] = (idx < n) ? cnt[idx] : 0u; s += v[i]; }
    lds[t] = s; __syncthreads();
    for (int st = 1; st < 256; st <<= 1) {
        const unsigned add = (t >= st) ? lds[t - st] : 0u;
        __syncthreads();
        lds[t] += add;
        __syncthreads();
    }
    unsigned excl = (t > 0 ? lds[t - 1] : 0u) + bsum[blockIdx.x];
#pragma unroll
    for (int i = 0; i < 8; ++i) {
        const int idx = base + i;
        if (idx < n) { off[idx] = excl; cursor[idx] = excl; excl += v[i]; }
    }
}

__global__ __launch_bounds__(256) void scatter_kernel(const int* __restrict__ ei,
                                                      unsigned* __restrict__ cursor,
                                                      int* __restrict__ sdst, int E) {
    const int e = blockIdx.x * 256 + threadIdx.x;
    if (e >= E) return;
    const int s = ei[e];
    const int d = ei[E + e];
    const unsigned pos = atomicAdd(&cursor[s], 1u);
    sdst[pos] = d;
}

// ---------------- Plan C: atomic fallback ----------------
__device__ __forceinline__ float edge_part(float hs, float hd, float a1, float a2, float a3) {
    float p = hd * a1;
    p = fmaf(leaky(hs + hd), a2, p);
    p = fmaf(leaky(hs - hd), a3, p);
    return p;
}

__global__ __launch_bounds__(256) void edge_kernel(const int* __restrict__ ei,
                                                   const float* __restrict__ h,
                                                   const float* __restrict__ a,
                                                   float* __restrict__ hprime,
                                                   float* __restrict__ rowsum,
                                                   int E) {
    const int lane = threadIdx.x & 63;
    const int wave = (int)((blockIdx.x * blockDim.x + threadIdx.x) >> 6);
    const int nwaves = (int)((gridDim.x * blockDim.x) >> 6);
    const float a0 = a[lane], a1 = a[64 + lane], a2 = a[128 + lane], a3 = a[192 + lane];
    for (int e = wave; e < E; e += nwaves) {
        const int s = ei[e];
        const int d = ei[E + e];
        const float hs = h[(size_t)s * F_OUT + lane];
        const float hd = h[(size_t)d * F_OUT + lane];
        const float part = wave_sum(hs * a0 + edge_part(hs, hd, a1, a2, a3));
        const float ee = __expf(-leaky(part));
        atomicAdd(&hprime[(size_t)s * F_OUT + lane], ee * hd);
        if (lane == 0) atomicAdd(&rowsum[s], ee);
    }
}

__global__ __launch_bounds__(256) void finalize(float* __restrict__ out,
                                                const float* __restrict__ rowsum,
                                                int total) {
    const int i = blockIdx.x * blockDim.x + threadIdx.x;
    if (i < total) out[i] = out[i] / (rowsum[i >> 6] + 1e-16f);
}

static inline size_t align_up(size_t v, size_t a) { return (v + a - 1) & ~(a - 1); }

extern "C" void kernel_launch(void* const* d_in, const int* in_sizes, int n_in,
                              void* d_out, int out_size, void* d_ws, size_t ws_size,
                              hipStream_t stream) {
    const float* x  = (const float*)d_in[0];
    const int*   ei = (const int*)d_in[1];
    const float* W  = (const float*)d_in[2];
    const float* a  = (const float*)d_in[3];

    const int N = in_sizes[0] / F_IN;
    const int E = in_sizes[1] / 2;
    float* out = (float*)d_out;

    const int NB = (N + BNODES - 1) >> BSHIFT;
    const int ngemm = (N + 63) / 64;
    const int nbt = (E + BIN_TILE - 1) / BIN_TILE;
    const unsigned meanFill = (NB > 0) ? (unsigned)(E / NB) : 0u;

    char* ws = (char*)d_ws;
    const size_t szh16  = align_up((size_t)N * F_OUT * 2, 256);
    const size_t szoff  = align_up(((size_t)N + 1) * 4, 256);
    const size_t szedge = align_up((size_t)E * 4 + 64, 256);
    const size_t szbin  = align_up((size_t)NB * BCAP * 4 + 64, 256);

    // common prefix: h16 | off | sdst
    const size_t off_b  = szh16;
    const size_t sdst_b = off_b + szoff;
    // plan A tail: binned | gcur | bcnt | bbase
    const size_t binned_b = sdst_b + szedge;
    const size_t gcur_b   = binned_b + szbin;
    const size_t bcnt_b   = gcur_b + 4096;
    const size_t bbase_b  = bcnt_b + 4096;
    const size_t needA    = bbase_b + 4096;
    // plan B tail: cursor | cnt | bsum
    const size_t cursor_b = sdst_b + szedge;
    const size_t cnt_b    = cursor_b + align_up((size_t)N * 4, 256);
    const size_t bsum_b   = cnt_b + align_up((size_t)N * 4, 256);
    const size_t needB    = bsum_b + 4096;

    uint2* h16 = (uint2*)ws;
    const int nodeBlocks = 2048;

    if (ws_size >= needA && N <= (1 << 17) && NB <= 1024 && meanFill <= (BCAP * 3u) / 4u) {
        unsigned* off    = (unsigned*)(ws + off_b);
        int*      sdst   = (int*)(ws + sdst_b);
        unsigned* binned = (unsigned*)(ws + binned_b);
        unsigned* gcur   = (unsigned*)(ws + gcur_b);
        unsigned* bcnt   = (unsigned*)(ws + bcnt_b);
        unsigned* bbase  = (unsigned*)(ws + bbase_b);

        gemm_xw<<<ngemm, 256, 0, stream>>>(x, W, nullptr, h16, gcur, N, NB, BCAP, 1);
        binA<<<nbt, 256, 0, stream>>>(ei, gcur, binned, E, NB, BCAP);
        scan_counts<<<1, 256, 0, stream>>>(gcur, bcnt, bbase, NB, BCAP);
        binB<<<NB, 256, 0, stream>>>(binned, bbase, bcnt, off, sdst, N, NB, BCAP);
        node_kernel<<<nodeBlocks, 256, 0, stream>>>(off, sdst, h16, a, out, N);
    } else if (ws_size >= needB && N <= (1 << 17)) {
        unsigned* off    = (unsigned*)(ws + off_b);
        int*      sdst   = (int*)(ws + sdst_b);
        unsigned* cursor = (unsigned*)(ws + cursor_b);
        unsigned* cnt    = (unsigned*)(ws + cnt_b);
        unsigned* bsum   = (unsigned*)(ws + bsum_b);
        const int nb2 = (N + 2047) / 2048;

        hipMemsetAsync(cnt, 0, (size_t)N * 4, stream);
        gemm_xw<<<ngemm, 256, 0, stream>>>(x, W, nullptr, h16, nullptr, N, NB, BCAP, 1);
        hist_kernel<<<(E + 255) / 256, 256, 0, stream>>>(ei, cnt, E);
        scan1<<<nb2, 256, 0, stream>>>(cnt, bsum, N);
        scan2<<<1, 128, 0, stream>>>(bsum, off, nb2, N);
        scan3<<<nb2, 256, 0, stream>>>(cnt, bsum, off, cursor, N);
        scatter_kernel<<<(E + 255) / 256, 256, 0, stream>>>(ei, cursor, sdst, E);
        node_kernel<<<nodeBlocks, 256, 0, stream>>>(off, sdst, h16, a, out, N);
    } else {
        float* h32    = (float*)ws;
        float* rowsum = (float*)(ws + align_up((size_t)N * F_OUT * 4, 256));
        hipMemsetAsync(d_out, 0, (size_t)N * F_OUT * sizeof(float), stream);
        hipMemsetAsync(rowsum, 0, (size_t)N * sizeof(float), stream);
        gemm_xw<<<ngemm, 256, 0, stream>>>(x, W, h32, nullptr, nullptr, N, NB, BCAP, 2);
        edge_kernel<<<2048, 256, 0, stream>>>(ei, h32, a, out, rowsum, E);
        finalize<<<((size_t)N * F_OUT + 255) / 256, 256, 0, stream>>>(out, rowsum, N * F_OUT);
    }
}